// Round 1
// baseline (2014.020 us; speedup 1.0000x reference)
//
#include <hip/hip_runtime.h>
#include <math.h>

// Problem constants (match reference file)
constexpr int U_N = 100000;
constexpr int SI_N = 50000;
constexpr int TI_N = 40000;
constexpr int D = 64;
constexpr int B = 8192;
constexpr int NS = U_N + SI_N;   // 150000 rows in source graph
constexpr int NT = U_N + TI_N;   // 140000 rows in target graph
constexpr int SLOTS = 3 * B;     // compact agg slots: users | pos items | neg items

__device__ __forceinline__ float wave_sum(float x) {
#pragma unroll
  for (int m = 32; m; m >>= 1) x += __shfl_xor(x, m, 64);
  return x;
}

// softplus(z) = log(1+e^z), numerically stable
__device__ __forceinline__ float softplus_f(float z) {
  return fmaxf(z, 0.f) + log1pf(expf(-fabsf(z)));
}

// ---------------------------------------------------------------------------
// map[row] = slot (any consistent winner among duplicate rows); -1 = untouched
__global__ __launch_bounds__(256) void k_build_maps(
    const int* __restrict__ user, const int* __restrict__ spos, const int* __restrict__ sneg,
    const int* __restrict__ tpos, const int* __restrict__ tneg,
    int* __restrict__ map_s, int* __restrict__ map_t) {
  int t = blockIdx.x * blockDim.x + threadIdx.x;
  if (t >= 3 * B) return;
  if (t < B) {
    int u = user[t];
    map_s[u] = t;
    map_t[u] = t;
  } else if (t < 2 * B) {
    int b = t - B;
    map_s[U_N + spos[b]] = t;
    map_t[U_N + tpos[b]] = t;
  } else {
    int b = t - 2 * B;
    map_s[U_N + sneg[b]] = t;
    map_t[U_N + tneg[b]] = t;
  }
}

// ---------------------------------------------------------------------------
// Classify the device layout of the bool mask arrays from byte patterns.
// det[0]: nonzero bytes at offsets %4!=0  (uint8:~3072, int32:0, f32:~2048)
// det[1]: bytes with value >1            (uint8:0,     int32:0, f32:~2048)
__global__ __launch_bounds__(256) void k_detect(const unsigned char* __restrict__ m, int n,
                                                int* __restrict__ det) {
  int t = threadIdx.x;
  int cb = 0, cc = 0;
  for (int i = t; i < n; i += 256) {
    unsigned char v = m[i];
    if ((i & 3) && v) cb++;
    if (v > 1) cc++;
  }
#pragma unroll
  for (int off = 32; off; off >>= 1) {
    cb += __shfl_xor(cb, off, 64);
    cc += __shfl_xor(cc, off, 64);
  }
  __shared__ int sb[4], sc[4];
  if ((t & 63) == 0) { sb[t >> 6] = cb; sc[t >> 6] = cc; }
  __syncthreads();
  if (t == 0) {
    det[0] = sb[0] + sb[1] + sb[2] + sb[3];
    det[1] = sc[0] + sc[1] + sc[2] + sc[3];
  }
}

// ---------------------------------------------------------------------------
// One wave per edge; lane = dim. Filter by map, gather emb[col], atomic into
// compact slot buffers for int & pop factors.
__global__ __launch_bounds__(256) void k_scatter(
    const int* __restrict__ rows, const int* __restrict__ cols, const float* __restrict__ vals,
    const float* __restrict__ drop_i, const float* __restrict__ drop_p,
    const int* __restrict__ map,
    const float* __restrict__ eu_i, const float* __restrict__ ei_i,
    const float* __restrict__ eu_p, const float* __restrict__ ei_p,
    float* __restrict__ aggA, float* __restrict__ aggB, int nnz) {
  int lane = threadIdx.x & 63;
  int wave = (blockIdx.x * blockDim.x + threadIdx.x) >> 6;
  int nwaves = (gridDim.x * blockDim.x) >> 6;
  for (int e = wave; e < nnz; e += nwaves) {
    int r = rows[e];
    int slot = map[r];              // wave-uniform
    if (slot < 0) continue;         // ~84% of edges skip here
    int c = cols[e];
    float v = vals[e];
    float wi = v * drop_i[e];
    float wp = v * drop_p[e];
    const float* si = (c < U_N) ? (eu_i + (size_t)c * D) : (ei_i + (size_t)(c - U_N) * D);
    const float* sp = (c < U_N) ? (eu_p + (size_t)c * D) : (ei_p + (size_t)(c - U_N) * D);
    float* dA = aggA + (size_t)slot * D;
    float* dB = aggB + (size_t)slot * D;
    if (wi != 0.f) atomicAdd(dA + lane, wi * si[lane]);
    if (wp != 0.f) atomicAdd(dB + lane, wp * sp[lane]);
  }
}

// ---------------------------------------------------------------------------
// One wave per sample: dots for (pos,neg) x (int,pop); out = 0.25*(e+a)·(e+a)
__global__ __launch_bounds__(256) void k_dots(
    const int* __restrict__ user, const int* __restrict__ pos, const int* __restrict__ neg,
    const float* __restrict__ eu_i, const float* __restrict__ ei_i,
    const float* __restrict__ eu_p, const float* __restrict__ ei_p,
    const int* __restrict__ map, const float* __restrict__ aggA, const float* __restrict__ aggB,
    float* __restrict__ dpi, float* __restrict__ dni,
    float* __restrict__ dpp, float* __restrict__ dnp_) {
  int lane = threadIdx.x & 63;
  int b = (blockIdx.x * blockDim.x + threadIdx.x) >> 6;
  if (b >= B) return;
  int u = user[b], p = pos[b], n = neg[b];
  int su = map[u], sp = map[U_N + p], sn = map[U_N + n];
  float oui = eu_i[(size_t)u * D + lane] + aggA[(size_t)su * D + lane];
  float oup = eu_p[(size_t)u * D + lane] + aggB[(size_t)su * D + lane];
  float opi = ei_i[(size_t)p * D + lane] + aggA[(size_t)sp * D + lane];
  float opp = ei_p[(size_t)p * D + lane] + aggB[(size_t)sp * D + lane];
  float oni = ei_i[(size_t)n * D + lane] + aggA[(size_t)sn * D + lane];
  float onp = ei_p[(size_t)n * D + lane] + aggB[(size_t)sn * D + lane];
  float s0 = wave_sum(oui * opi);
  float s1 = wave_sum(oui * oni);
  float s2 = wave_sum(oup * opp);
  float s3 = wave_sum(oup * onp);
  if (lane == 0) {
    dpi[b] = 0.25f * s0;
    dni[b] = 0.25f * s1;
    dpp[b] = 0.25f * s2;
    dnp_[b] = 0.25f * s3;
  }
}

// ---------------------------------------------------------------------------
// Per-sample BPR-style losses; all are means over B. acc[0] += sum/B
__global__ __launch_bounds__(256) void k_bpr(
    const unsigned char* __restrict__ ms8, const unsigned char* __restrict__ mt8,
    const float* __restrict__ dots, const int* __restrict__ det,
    float* __restrict__ acc) {
  int b = blockIdx.x * blockDim.x + threadIdx.x;
  const float* spi = dots;
  const float* sni = dots + B;
  const float* spp = dots + 2 * B;
  const float* snp = dots + 3 * B;
  const float* tpi = dots + 4 * B;
  const float* tni = dots + 5 * B;
  const float* tpp = dots + 6 * B;
  const float* tnp = dots + 7 * B;
  float contrib = 0.f;
  if (b < B) {
    int db = det[0], dc = det[1];
    float ms, mt;
    if (dc > 100) {  // float32 layout
      ms = (((const float*)ms8)[b] != 0.f) ? 1.f : 0.f;
      mt = (((const float*)mt8)[b] != 0.f) ? 1.f : 0.f;
    } else if (db > 100) {  // uint8 (numpy bool) layout
      ms = ms8[b] ? 1.f : 0.f;
      mt = mt8[b] ? 1.f : 0.f;
    } else {  // int32 layout
      ms = ((const int*)ms8)[b] ? 1.f : 0.f;
      mt = ((const int*)mt8)[b] ? 1.f : 0.f;
    }
    float l_int_s = ms * softplus_f(sni[b] - spi[b]);
    float l_pop_s = ms * softplus_f(spp[b] - snp[b]) + (1.f - ms) * softplus_f(snp[b] - spp[b]);
    float l_tot_s = softplus_f((sni[b] + snp[b]) - (spi[b] + spp[b]));
    float l_int_t = mt * softplus_f(tni[b] - tpi[b]);
    float l_pop_t = mt * softplus_f(tpp[b] - tnp[b]) + (1.f - mt) * softplus_f(tnp[b] - tpp[b]);
    float l_tot_t = softplus_f((tni[b] + tnp[b]) - (tpi[b] + tpp[b]));
    contrib = (l_tot_s + l_tot_t + 0.1f * (l_int_s + l_int_t) + 0.1f * (l_pop_s + l_pop_t)) *
              (1.f / (float)B);
  }
#pragma unroll
  for (int off = 32; off; off >>= 1) contrib += __shfl_xor(contrib, off, 64);
  __shared__ float wsum_[4];
  if ((threadIdx.x & 63) == 0) wsum_[threadIdx.x >> 6] = contrib;
  __syncthreads();
  if (threadIdx.x == 0) atomicAdd(&acc[0], wsum_[0] + wsum_[1] + wsum_[2] + wsum_[3]);
}

// ---------------------------------------------------------------------------
// Masked L1 numerator + distinct-row count. One wave per row, lane = dim.
// Optionally processes a second (a2,b2) pair sharing the same mask (user case).
__global__ __launch_bounds__(256) void k_dis(
    const float* __restrict__ a, const float* __restrict__ bb,
    const float* __restrict__ a2, const float* __restrict__ b2,
    const int* __restrict__ map, int map_off, int nrows,
    float* __restrict__ num1, float* __restrict__ num2, float* __restrict__ cnt) {
  int lane = threadIdx.x & 63;
  int wave = (blockIdx.x * blockDim.x + threadIdx.x) >> 6;
  int nwaves = (gridDim.x * blockDim.x) >> 6;
  for (int r = wave; r < nrows; r += nwaves) {
    if (map[map_off + r] < 0) continue;  // wave-uniform
    size_t o = (size_t)r * D + lane;
    float s1 = wave_sum(fabsf(a[o] - bb[o]));
    float s2 = 0.f;
    if (a2) s2 = wave_sum(fabsf(a2[o] - b2[o]));
    if (lane == 0) {
      atomicAdd(num1, s1);
      if (num2) atomicAdd(num2, s2);
      if (cnt) atomicAdd(cnt, 1.f);
    }
  }
}

// ---------------------------------------------------------------------------
__global__ void k_final(const float* __restrict__ acc, float* __restrict__ out) {
  if (threadIdx.x == 0 && blockIdx.x == 0) {
    float cu = fmaxf(acc[5], 1.f);
    float cs = fmaxf(acc[6], 1.f);
    float ct = fmaxf(acc[7], 1.f);
    float dis = acc[1] / (cu * (float)D) + acc[2] / (cs * (float)D) +
                acc[3] / (cu * (float)D) + acc[4] / (ct * (float)D);
    out[0] = acc[0] - 0.01f * dis;
  }
}

// ---------------------------------------------------------------------------
extern "C" void kernel_launch(void* const* d_in, const int* in_sizes, int n_in,
                              void* d_out, int out_size, void* d_ws, size_t ws_size,
                              hipStream_t stream) {
  const int* user = (const int*)d_in[0];
  const int* spos = (const int*)d_in[1];
  const int* sneg = (const int*)d_in[2];
  const int* tpos = (const int*)d_in[3];
  const int* tneg = (const int*)d_in[4];
  const unsigned char* mask_s = (const unsigned char*)d_in[5];
  const unsigned char* mask_t = (const unsigned char*)d_in[6];
  const float* su_int = (const float*)d_in[7];
  const float* si_int = (const float*)d_in[8];
  const float* tu_int = (const float*)d_in[9];
  const float* ti_int = (const float*)d_in[10];
  const float* su_pop = (const float*)d_in[11];
  const float* si_pop = (const float*)d_in[12];
  const float* tu_pop = (const float*)d_in[13];
  const float* ti_pop = (const float*)d_in[14];
  const int* s_rows = (const int*)d_in[15];
  const int* s_cols = (const int*)d_in[16];
  const float* s_vals = (const float*)d_in[17];
  const int* t_rows = (const int*)d_in[18];
  const int* t_cols = (const int*)d_in[19];
  const float* t_vals = (const float*)d_in[20];
  const float* drop_s_int = (const float*)d_in[21];
  const float* drop_t_int = (const float*)d_in[22];
  const float* drop_s_pop = (const float*)d_in[23];
  const float* drop_t_pop = (const float*)d_in[24];
  const int nnz_s = in_sizes[15];
  const int nnz_t = in_sizes[18];

  // Workspace layout (~14 MB)
  float* aggA = (float*)d_ws;                       // SLOTS*D  (int factor)
  float* aggB = aggA + (size_t)SLOTS * D;           // SLOTS*D  (pop factor)
  int* map_s = (int*)(aggB + (size_t)SLOTS * D);    // NS
  int* map_t = map_s + NS;                          // NT
  float* dots = (float*)(map_t + NT);               // 8*B
  float* acc = dots + 8 * B;                        // 16 floats (0:bpr, 1-4:nums, 5-7:cnts)
  int* det = (int*)(acc + 8);                       // 2 ints (mask-layout detection)

  hipMemsetAsync(acc, 0, 16 * sizeof(float), stream);
  hipMemsetAsync(map_s, 0xFF, (size_t)NS * sizeof(int), stream);   // -1
  hipMemsetAsync(map_t, 0xFF, (size_t)NT * sizeof(int), stream);   // -1
  hipMemsetAsync(aggA, 0, (size_t)2 * SLOTS * D * sizeof(float), stream);

  k_build_maps<<<(3 * B + 255) / 256, 256, 0, stream>>>(user, spos, sneg, tpos, tneg, map_s, map_t);
  k_detect<<<1, 256, 0, stream>>>(mask_s, B, det);

  // ---- source graph (int + pop factors share edge reads) ----
  k_scatter<<<8192, 256, 0, stream>>>(s_rows, s_cols, s_vals, drop_s_int, drop_s_pop,
                                      map_s, su_int, si_int, su_pop, si_pop, aggA, aggB, nnz_s);
  k_dots<<<(B * 64) / 256, 256, 0, stream>>>(user, spos, sneg, su_int, si_int, su_pop, si_pop,
                                             map_s, aggA, aggB,
                                             dots, dots + B, dots + 2 * B, dots + 3 * B);

  // ---- target graph (reuse agg buffers) ----
  hipMemsetAsync(aggA, 0, (size_t)2 * SLOTS * D * sizeof(float), stream);
  k_scatter<<<8192, 256, 0, stream>>>(t_rows, t_cols, t_vals, drop_t_int, drop_t_pop,
                                      map_t, tu_int, ti_int, tu_pop, ti_pop, aggA, aggB, nnz_t);
  k_dots<<<(B * 64) / 256, 256, 0, stream>>>(user, tpos, tneg, tu_int, ti_int, tu_pop, ti_pop,
                                             map_t, aggA, aggB,
                                             dots + 4 * B, dots + 5 * B, dots + 6 * B, dots + 7 * B);

  // ---- losses ----
  k_bpr<<<(B + 255) / 256, 256, 0, stream>>>(mask_s, mask_t, dots, det, acc);
  k_dis<<<2048, 256, 0, stream>>>(su_int, su_pop, tu_int, tu_pop, map_s, 0, U_N,
                                  acc + 1, acc + 3, acc + 5);
  k_dis<<<2048, 256, 0, stream>>>(si_int, si_pop, nullptr, nullptr, map_s, U_N, SI_N,
                                  acc + 2, nullptr, acc + 6);
  k_dis<<<2048, 256, 0, stream>>>(ti_int, ti_pop, nullptr, nullptr, map_t, U_N, TI_N,
                                  acc + 4, nullptr, acc + 7);
  k_final<<<1, 64, 0, stream>>>(acc, (float*)d_out);
}

// Round 2
// 1480.163 us; speedup vs baseline: 1.3607x; 1.3607x over previous
//
#include <hip/hip_runtime.h>
#include <math.h>

// Problem constants (match reference file)
constexpr int U_N = 100000;
constexpr int SI_N = 50000;
constexpr int TI_N = 40000;
constexpr int D = 64;
constexpr int B = 8192;
constexpr int NS = U_N + SI_N;   // 150000 rows in source graph
constexpr int NT = U_N + TI_N;   // 140000 rows in target graph
constexpr int SLOTS = 3 * B;     // compact agg slots: users | pos items | neg items
constexpr int CAP = 64;          // bucket capacity per slot (Poisson lambda ~21)
constexpr int OVCAP = 4096;      // overflow list capacity (statistically never used)

__device__ __forceinline__ float wave_sum(float x) {
#pragma unroll
  for (int m = 32; m; m >>= 1) x += __shfl_xor(x, m, 64);
  return x;
}

// softplus(z) = log(1+e^z), numerically stable
__device__ __forceinline__ float softplus_f(float z) {
  return fmaxf(z, 0.f) + log1pf(expf(-fabsf(z)));
}

// ---------------------------------------------------------------------------
// map[row] = slot (any consistent winner among duplicate rows); -1 = untouched
__global__ __launch_bounds__(256) void k_build_maps(
    const int* __restrict__ user, const int* __restrict__ spos, const int* __restrict__ sneg,
    const int* __restrict__ tpos, const int* __restrict__ tneg,
    int* __restrict__ map_s, int* __restrict__ map_t) {
  int t = blockIdx.x * blockDim.x + threadIdx.x;
  if (t >= 3 * B) return;
  if (t < B) {
    int u = user[t];
    map_s[u] = t;
    map_t[u] = t;
  } else if (t < 2 * B) {
    int b = t - B;
    map_s[U_N + spos[b]] = t;
    map_t[U_N + tpos[b]] = t;
  } else {
    int b = t - 2 * B;
    map_s[U_N + sneg[b]] = t;
    map_t[U_N + tneg[b]] = t;
  }
}

// ---------------------------------------------------------------------------
// Classify the device layout of the bool mask arrays from byte patterns.
__global__ __launch_bounds__(256) void k_detect(const unsigned char* __restrict__ m, int n,
                                                int* __restrict__ det) {
  int t = threadIdx.x;
  int cb = 0, cc = 0;
  for (int i = t; i < n; i += 256) {
    unsigned char v = m[i];
    if ((i & 3) && v) cb++;
    if (v > 1) cc++;
  }
#pragma unroll
  for (int off = 32; off; off >>= 1) {
    cb += __shfl_xor(cb, off, 64);
    cc += __shfl_xor(cc, off, 64);
  }
  __shared__ int sb[4], sc[4];
  if ((t & 63) == 0) { sb[t >> 6] = cb; sc[t >> 6] = cc; }
  __syncthreads();
  if (t == 0) {
    det[0] = sb[0] + sb[1] + sb[2] + sb[3];
    det[1] = sc[0] + sc[1] + sc[2] + sc[3];
  }
}

// ---------------------------------------------------------------------------
// Phase A: one THREAD per edge. Filter by map; append surviving edge ids into
// per-slot buckets. Overflow (p~1e-8) goes to a small list handled later.
__global__ __launch_bounds__(256) void k_compact(
    const int* __restrict__ rows, const int* __restrict__ map,
    int* __restrict__ cnt, int* __restrict__ bucket,
    int* __restrict__ ovcnt, int* __restrict__ ov, int nnz) {
  int e = blockIdx.x * 256 + threadIdx.x;
  if (e >= nnz) return;
  int slot = map[rows[e]];
  if (slot < 0) return;
  int pos = atomicAdd(&cnt[slot], 1);
  if (pos < CAP) {
    bucket[slot * CAP + pos] = e;
  } else {
    int o = atomicAdd(ovcnt, 1);
    if (o < OVCAP) { ov[2 * o] = slot; ov[2 * o + 1] = e; }
  }
}

// ---------------------------------------------------------------------------
// Phase B: one WAVE per slot, lane = dim. Lane l pre-loads edge l's metadata,
// shfl-broadcast loop gathers emb rows (coalesced 256B) and accumulates in
// registers for both factors. Single plain store per slot per factor.
__global__ __launch_bounds__(256) void k_accum(
    const int* __restrict__ cols, const float* __restrict__ vals,
    const float* __restrict__ di, const float* __restrict__ dp,
    const int* __restrict__ cnt, const int* __restrict__ bucket,
    const float* __restrict__ eu_i, const float* __restrict__ ei_i,
    const float* __restrict__ eu_p, const float* __restrict__ ei_p,
    float* __restrict__ aggA, float* __restrict__ aggB) {
  int lane = threadIdx.x & 63;
  int s = (blockIdx.x * 256 + threadIdx.x) >> 6;
  if (s >= SLOTS) return;
  int m = min(cnt[s], CAP);
  int c = 0;
  float wi = 0.f, wp = 0.f;
  if (lane < m) {
    int e = bucket[s * CAP + lane];
    c = cols[e];
    float v = vals[e];
    wi = v * di[e];
    wp = v * dp[e];
  }
  float aI = 0.f, aP = 0.f;
  for (int k = 0; k < m; ++k) {
    int ck = __shfl(c, k, 64);
    float wik = __shfl(wi, k, 64);
    float wpk = __shfl(wp, k, 64);
    const float* bi = (ck < U_N) ? (eu_i + (size_t)ck * D) : (ei_i + (size_t)(ck - U_N) * D);
    const float* bp = (ck < U_N) ? (eu_p + (size_t)ck * D) : (ei_p + (size_t)(ck - U_N) * D);
    aI = fmaf(wik, bi[lane], aI);
    aP = fmaf(wpk, bp[lane], aP);
  }
  aggA[(size_t)s * D + lane] = aI;
  aggB[(size_t)s * D + lane] = aP;
}

// ---------------------------------------------------------------------------
// Phase C: overflow fixup (normally empty). One wave per overflow entry.
__global__ __launch_bounds__(256) void k_over(
    const int* __restrict__ ovcnt, const int* __restrict__ ov,
    const int* __restrict__ cols, const float* __restrict__ vals,
    const float* __restrict__ di, const float* __restrict__ dp,
    const float* __restrict__ eu_i, const float* __restrict__ ei_i,
    const float* __restrict__ eu_p, const float* __restrict__ ei_p,
    float* __restrict__ aggA, float* __restrict__ aggB) {
  int n = min(*ovcnt, OVCAP);
  int lane = threadIdx.x & 63;
  int w = threadIdx.x >> 6;
  for (int i = w; i < n; i += 4) {
    int slot = ov[2 * i], e = ov[2 * i + 1];
    int c = cols[e];
    float v = vals[e];
    float wi = v * di[e], wp = v * dp[e];
    const float* bi = (c < U_N) ? (eu_i + (size_t)c * D) : (ei_i + (size_t)(c - U_N) * D);
    const float* bp = (c < U_N) ? (eu_p + (size_t)c * D) : (ei_p + (size_t)(c - U_N) * D);
    atomicAdd(&aggA[(size_t)slot * D + lane], wi * bi[lane]);
    atomicAdd(&aggB[(size_t)slot * D + lane], wp * bp[lane]);
  }
}

// ---------------------------------------------------------------------------
// One wave per sample: dots for (pos,neg) x (int,pop); out = 0.25*(e+a)·(e+a)
__global__ __launch_bounds__(256) void k_dots(
    const int* __restrict__ user, const int* __restrict__ pos, const int* __restrict__ neg,
    const float* __restrict__ eu_i, const float* __restrict__ ei_i,
    const float* __restrict__ eu_p, const float* __restrict__ ei_p,
    const int* __restrict__ map, const float* __restrict__ aggA, const float* __restrict__ aggB,
    float* __restrict__ dpi, float* __restrict__ dni,
    float* __restrict__ dpp, float* __restrict__ dnp_) {
  int lane = threadIdx.x & 63;
  int b = (blockIdx.x * blockDim.x + threadIdx.x) >> 6;
  if (b >= B) return;
  int u = user[b], p = pos[b], n = neg[b];
  int su = map[u], sp = map[U_N + p], sn = map[U_N + n];
  float oui = eu_i[(size_t)u * D + lane] + aggA[(size_t)su * D + lane];
  float oup = eu_p[(size_t)u * D + lane] + aggB[(size_t)su * D + lane];
  float opi = ei_i[(size_t)p * D + lane] + aggA[(size_t)sp * D + lane];
  float opp = ei_p[(size_t)p * D + lane] + aggB[(size_t)sp * D + lane];
  float oni = ei_i[(size_t)n * D + lane] + aggA[(size_t)sn * D + lane];
  float onp = ei_p[(size_t)n * D + lane] + aggB[(size_t)sn * D + lane];
  float s0 = wave_sum(oui * opi);
  float s1 = wave_sum(oui * oni);
  float s2 = wave_sum(oup * opp);
  float s3 = wave_sum(oup * onp);
  if (lane == 0) {
    dpi[b] = 0.25f * s0;
    dni[b] = 0.25f * s1;
    dpp[b] = 0.25f * s2;
    dnp_[b] = 0.25f * s3;
  }
}

// ---------------------------------------------------------------------------
// Per-sample BPR-style losses; all are means over B. acc[0] += sum/B
__global__ __launch_bounds__(256) void k_bpr(
    const unsigned char* __restrict__ ms8, const unsigned char* __restrict__ mt8,
    const float* __restrict__ dots, const int* __restrict__ det,
    float* __restrict__ acc) {
  int b = blockIdx.x * blockDim.x + threadIdx.x;
  const float* spi = dots;
  const float* sni = dots + B;
  const float* spp = dots + 2 * B;
  const float* snp = dots + 3 * B;
  const float* tpi = dots + 4 * B;
  const float* tni = dots + 5 * B;
  const float* tpp = dots + 6 * B;
  const float* tnp = dots + 7 * B;
  float contrib = 0.f;
  if (b < B) {
    int db = det[0], dc = det[1];
    float ms, mt;
    if (dc > 100) {  // float32 layout
      ms = (((const float*)ms8)[b] != 0.f) ? 1.f : 0.f;
      mt = (((const float*)mt8)[b] != 0.f) ? 1.f : 0.f;
    } else if (db > 100) {  // uint8 (numpy bool) layout
      ms = ms8[b] ? 1.f : 0.f;
      mt = mt8[b] ? 1.f : 0.f;
    } else {  // int32 layout
      ms = ((const int*)ms8)[b] ? 1.f : 0.f;
      mt = ((const int*)mt8)[b] ? 1.f : 0.f;
    }
    float l_int_s = ms * softplus_f(sni[b] - spi[b]);
    float l_pop_s = ms * softplus_f(spp[b] - snp[b]) + (1.f - ms) * softplus_f(snp[b] - spp[b]);
    float l_tot_s = softplus_f((sni[b] + snp[b]) - (spi[b] + spp[b]));
    float l_int_t = mt * softplus_f(tni[b] - tpi[b]);
    float l_pop_t = mt * softplus_f(tpp[b] - tnp[b]) + (1.f - mt) * softplus_f(tnp[b] - tpp[b]);
    float l_tot_t = softplus_f((tni[b] + tnp[b]) - (tpi[b] + tpp[b]));
    contrib = (l_tot_s + l_tot_t + 0.1f * (l_int_s + l_int_t) + 0.1f * (l_pop_s + l_pop_t)) *
              (1.f / (float)B);
  }
#pragma unroll
  for (int off = 32; off; off >>= 1) contrib += __shfl_xor(contrib, off, 64);
  __shared__ float wsum_[4];
  if ((threadIdx.x & 63) == 0) wsum_[threadIdx.x >> 6] = contrib;
  __syncthreads();
  if (threadIdx.x == 0) atomicAdd(&acc[0], wsum_[0] + wsum_[1] + wsum_[2] + wsum_[3]);
}

// ---------------------------------------------------------------------------
// Masked L1 numerator + distinct-row count. One wave per row, lane = dim.
__global__ __launch_bounds__(256) void k_dis(
    const float* __restrict__ a, const float* __restrict__ bb,
    const float* __restrict__ a2, const float* __restrict__ b2,
    const int* __restrict__ map, int map_off, int nrows,
    float* __restrict__ num1, float* __restrict__ num2, float* __restrict__ cnt) {
  int lane = threadIdx.x & 63;
  int wave = (blockIdx.x * blockDim.x + threadIdx.x) >> 6;
  int nwaves = (gridDim.x * blockDim.x) >> 6;
  for (int r = wave; r < nrows; r += nwaves) {
    if (map[map_off + r] < 0) continue;  // wave-uniform
    size_t o = (size_t)r * D + lane;
    float s1 = wave_sum(fabsf(a[o] - bb[o]));
    float s2 = 0.f;
    if (a2) s2 = wave_sum(fabsf(a2[o] - b2[o]));
    if (lane == 0) {
      atomicAdd(num1, s1);
      if (num2) atomicAdd(num2, s2);
      if (cnt) atomicAdd(cnt, 1.f);
    }
  }
}

// ---------------------------------------------------------------------------
__global__ void k_final(const float* __restrict__ acc, float* __restrict__ out) {
  if (threadIdx.x == 0 && blockIdx.x == 0) {
    float cu = fmaxf(acc[5], 1.f);
    float cs = fmaxf(acc[6], 1.f);
    float ct = fmaxf(acc[7], 1.f);
    float dis = acc[1] / (cu * (float)D) + acc[2] / (cs * (float)D) +
                acc[3] / (cu * (float)D) + acc[4] / (ct * (float)D);
    out[0] = acc[0] - 0.01f * dis;
  }
}

// ---------------------------------------------------------------------------
extern "C" void kernel_launch(void* const* d_in, const int* in_sizes, int n_in,
                              void* d_out, int out_size, void* d_ws, size_t ws_size,
                              hipStream_t stream) {
  const int* user = (const int*)d_in[0];
  const int* spos = (const int*)d_in[1];
  const int* sneg = (const int*)d_in[2];
  const int* tpos = (const int*)d_in[3];
  const int* tneg = (const int*)d_in[4];
  const unsigned char* mask_s = (const unsigned char*)d_in[5];
  const unsigned char* mask_t = (const unsigned char*)d_in[6];
  const float* su_int = (const float*)d_in[7];
  const float* si_int = (const float*)d_in[8];
  const float* tu_int = (const float*)d_in[9];
  const float* ti_int = (const float*)d_in[10];
  const float* su_pop = (const float*)d_in[11];
  const float* si_pop = (const float*)d_in[12];
  const float* tu_pop = (const float*)d_in[13];
  const float* ti_pop = (const float*)d_in[14];
  const int* s_rows = (const int*)d_in[15];
  const int* s_cols = (const int*)d_in[16];
  const float* s_vals = (const float*)d_in[17];
  const int* t_rows = (const int*)d_in[18];
  const int* t_cols = (const int*)d_in[19];
  const float* t_vals = (const float*)d_in[20];
  const float* drop_s_int = (const float*)d_in[21];
  const float* drop_t_int = (const float*)d_in[22];
  const float* drop_s_pop = (const float*)d_in[23];
  const float* drop_t_pop = (const float*)d_in[24];
  const int nnz_s = in_sizes[15];
  const int nnz_t = in_sizes[18];

  // Workspace layout (~21 MB)
  float* aggA = (float*)d_ws;                       // SLOTS*D  (int factor)
  float* aggB = aggA + (size_t)SLOTS * D;           // SLOTS*D  (pop factor)
  int* map_s = (int*)(aggB + (size_t)SLOTS * D);    // NS
  int* map_t = map_s + NS;                          // NT
  float* dots = (float*)(map_t + NT);               // 8*B
  float* acc = dots + 8 * B;                        // 16 floats
  int* det = (int*)(acc + 16);                      // 2 ints
  int* cnt = det + 2;                               // SLOTS
  int* ovcnt = cnt + SLOTS;                         // 1
  int* ov = ovcnt + 1;                              // 2*OVCAP
  int* bucket = ov + 2 * OVCAP;                     // SLOTS*CAP

  hipMemsetAsync(acc, 0, 16 * sizeof(float), stream);
  hipMemsetAsync(map_s, 0xFF, (size_t)NS * sizeof(int), stream);   // -1
  hipMemsetAsync(map_t, 0xFF, (size_t)NT * sizeof(int), stream);   // -1
  hipMemsetAsync(cnt, 0, (size_t)(SLOTS + 1) * sizeof(int), stream); // cnt + ovcnt

  k_build_maps<<<(3 * B + 255) / 256, 256, 0, stream>>>(user, spos, sneg, tpos, tneg, map_s, map_t);
  k_detect<<<1, 256, 0, stream>>>(mask_s, B, det);

  // ---- source graph ----
  k_compact<<<(nnz_s + 255) / 256, 256, 0, stream>>>(s_rows, map_s, cnt, bucket, ovcnt, ov, nnz_s);
  k_accum<<<SLOTS / 4, 256, 0, stream>>>(s_cols, s_vals, drop_s_int, drop_s_pop, cnt, bucket,
                                         su_int, si_int, su_pop, si_pop, aggA, aggB);
  k_over<<<1, 256, 0, stream>>>(ovcnt, ov, s_cols, s_vals, drop_s_int, drop_s_pop,
                                su_int, si_int, su_pop, si_pop, aggA, aggB);
  k_dots<<<(B * 64) / 256, 256, 0, stream>>>(user, spos, sneg, su_int, si_int, su_pop, si_pop,
                                             map_s, aggA, aggB,
                                             dots, dots + B, dots + 2 * B, dots + 3 * B);

  // ---- target graph (reuse bucket/cnt/agg buffers) ----
  hipMemsetAsync(cnt, 0, (size_t)(SLOTS + 1) * sizeof(int), stream);
  k_compact<<<(nnz_t + 255) / 256, 256, 0, stream>>>(t_rows, map_t, cnt, bucket, ovcnt, ov, nnz_t);
  k_accum<<<SLOTS / 4, 256, 0, stream>>>(t_cols, t_vals, drop_t_int, drop_t_pop, cnt, bucket,
                                         tu_int, ti_int, tu_pop, ti_pop, aggA, aggB);
  k_over<<<1, 256, 0, stream>>>(ovcnt, ov, t_cols, t_vals, drop_t_int, drop_t_pop,
                                tu_int, ti_int, tu_pop, ti_pop, aggA, aggB);
  k_dots<<<(B * 64) / 256, 256, 0, stream>>>(user, tpos, tneg, tu_int, ti_int, tu_pop, ti_pop,
                                             map_t, aggA, aggB,
                                             dots + 4 * B, dots + 5 * B, dots + 6 * B, dots + 7 * B);

  // ---- losses ----
  k_bpr<<<(B + 255) / 256, 256, 0, stream>>>(mask_s, mask_t, dots, det, acc);
  k_dis<<<2048, 256, 0, stream>>>(su_int, su_pop, tu_int, tu_pop, map_s, 0, U_N,
                                  acc + 1, acc + 3, acc + 5);
  k_dis<<<2048, 256, 0, stream>>>(si_int, si_pop, nullptr, nullptr, map_s, U_N, SI_N,
                                  acc + 2, nullptr, acc + 6);
  k_dis<<<2048, 256, 0, stream>>>(ti_int, ti_pop, nullptr, nullptr, map_t, U_N, TI_N,
                                  acc + 4, nullptr, acc + 7);
  k_final<<<1, 64, 0, stream>>>(acc, (float*)d_out);
}

// Round 3
// 548.166 us; speedup vs baseline: 3.6741x; 2.7002x over previous
//
#include <hip/hip_runtime.h>
#include <math.h>

// Problem constants (match reference file)
constexpr int U_N = 100000;
constexpr int SI_N = 50000;
constexpr int TI_N = 40000;
constexpr int D = 64;
constexpr int B = 8192;
constexpr int NS = U_N + SI_N;   // 150000 rows in source graph
constexpr int NT = U_N + TI_N;   // 140000 rows in target graph
constexpr int SLOTS = 3 * B;     // compact agg slots: users | pos items | neg items
constexpr int CAP = 64;          // bucket capacity per slot (Poisson lambda ~21)
constexpr int OVCAP = 4096;      // overflow list capacity (statistically never used)
constexpr int NROWS_ALL = U_N + SI_N + TI_N;  // fused dis-loss row space

__device__ __forceinline__ float wave_sum(float x) {
#pragma unroll
  for (int m = 32; m; m >>= 1) x += __shfl_xor(x, m, 64);
  return x;
}

// softplus(z) = log(1+e^z), numerically stable
__device__ __forceinline__ float softplus_f(float z) {
  return fmaxf(z, 0.f) + log1pf(expf(-fabsf(z)));
}

// ---------------------------------------------------------------------------
// map[row] = slot (any consistent winner among duplicate rows); -1 = untouched
__global__ __launch_bounds__(256) void k_build_maps(
    const int* __restrict__ user, const int* __restrict__ spos, const int* __restrict__ sneg,
    const int* __restrict__ tpos, const int* __restrict__ tneg,
    int* __restrict__ map_s, int* __restrict__ map_t) {
  int t = blockIdx.x * blockDim.x + threadIdx.x;
  if (t >= 3 * B) return;
  if (t < B) {
    int u = user[t];
    map_s[u] = t;
    map_t[u] = t;
  } else if (t < 2 * B) {
    int b = t - B;
    map_s[U_N + spos[b]] = t;
    map_t[U_N + tpos[b]] = t;
  } else {
    int b = t - 2 * B;
    map_s[U_N + sneg[b]] = t;
    map_t[U_N + tneg[b]] = t;
  }
}

// ---------------------------------------------------------------------------
// Classify the device layout of the bool mask arrays from byte patterns.
__global__ __launch_bounds__(256) void k_detect(const unsigned char* __restrict__ m, int n,
                                                int* __restrict__ det) {
  int t = threadIdx.x;
  int cb = 0, cc = 0;
  for (int i = t; i < n; i += 256) {
    unsigned char v = m[i];
    if ((i & 3) && v) cb++;
    if (v > 1) cc++;
  }
#pragma unroll
  for (int off = 32; off; off >>= 1) {
    cb += __shfl_xor(cb, off, 64);
    cc += __shfl_xor(cc, off, 64);
  }
  __shared__ int sb[4], sc[4];
  if ((t & 63) == 0) { sb[t >> 6] = cb; sc[t >> 6] = cc; }
  __syncthreads();
  if (t == 0) {
    det[0] = sb[0] + sb[1] + sb[2] + sb[3];
    det[1] = sc[0] + sc[1] + sc[2] + sc[3];
  }
}

// ---------------------------------------------------------------------------
// Phase A: one THREAD per edge. Filter by map; append surviving edge ids into
// per-slot buckets. Overflow (p~1e-8) goes to a small list handled later.
__global__ __launch_bounds__(256) void k_compact(
    const int* __restrict__ rows, const int* __restrict__ map,
    int* __restrict__ cnt, int* __restrict__ bucket,
    int* __restrict__ ovcnt, int* __restrict__ ov, int nnz) {
  int e = blockIdx.x * 256 + threadIdx.x;
  if (e >= nnz) return;
  int slot = map[rows[e]];
  if (slot < 0) return;
  int pos = atomicAdd(&cnt[slot], 1);
  if (pos < CAP) {
    bucket[slot * CAP + pos] = e;
  } else {
    int o = atomicAdd(ovcnt, 1);
    if (o < OVCAP) { ov[2 * o] = slot; ov[2 * o + 1] = e; }
  }
}

// ---------------------------------------------------------------------------
// Phase B: one WAVE per slot, lane = dim. Lane l pre-loads edge l's metadata,
// shfl-broadcast loop gathers emb rows (coalesced 256B) and accumulates in
// registers for both factors. Single plain store per slot per factor.
__global__ __launch_bounds__(256) void k_accum(
    const int* __restrict__ cols, const float* __restrict__ vals,
    const float* __restrict__ di, const float* __restrict__ dp,
    const int* __restrict__ cnt, const int* __restrict__ bucket,
    const float* __restrict__ eu_i, const float* __restrict__ ei_i,
    const float* __restrict__ eu_p, const float* __restrict__ ei_p,
    float* __restrict__ aggA, float* __restrict__ aggB) {
  int lane = threadIdx.x & 63;
  int s = (blockIdx.x * 256 + threadIdx.x) >> 6;
  if (s >= SLOTS) return;
  int m = min(cnt[s], CAP);
  int c = 0;
  float wi = 0.f, wp = 0.f;
  if (lane < m) {
    int e = bucket[s * CAP + lane];
    c = cols[e];
    float v = vals[e];
    wi = v * di[e];
    wp = v * dp[e];
  }
  float aI = 0.f, aP = 0.f;
  for (int k = 0; k < m; ++k) {
    int ck = __shfl(c, k, 64);
    float wik = __shfl(wi, k, 64);
    float wpk = __shfl(wp, k, 64);
    const float* bi = (ck < U_N) ? (eu_i + (size_t)ck * D) : (ei_i + (size_t)(ck - U_N) * D);
    const float* bp = (ck < U_N) ? (eu_p + (size_t)ck * D) : (ei_p + (size_t)(ck - U_N) * D);
    aI = fmaf(wik, bi[lane], aI);
    aP = fmaf(wpk, bp[lane], aP);
  }
  aggA[(size_t)s * D + lane] = aI;
  aggB[(size_t)s * D + lane] = aP;
}

// ---------------------------------------------------------------------------
// Phase C: overflow fixup (normally empty). One wave per overflow entry.
__global__ __launch_bounds__(256) void k_over(
    const int* __restrict__ ovcnt, const int* __restrict__ ov,
    const int* __restrict__ cols, const float* __restrict__ vals,
    const float* __restrict__ di, const float* __restrict__ dp,
    const float* __restrict__ eu_i, const float* __restrict__ ei_i,
    const float* __restrict__ eu_p, const float* __restrict__ ei_p,
    float* __restrict__ aggA, float* __restrict__ aggB) {
  int n = min(*ovcnt, OVCAP);
  int lane = threadIdx.x & 63;
  int w = threadIdx.x >> 6;
  for (int i = w; i < n; i += 4) {
    int slot = ov[2 * i], e = ov[2 * i + 1];
    int c = cols[e];
    float v = vals[e];
    float wi = v * di[e], wp = v * dp[e];
    const float* bi = (c < U_N) ? (eu_i + (size_t)c * D) : (ei_i + (size_t)(c - U_N) * D);
    const float* bp = (c < U_N) ? (eu_p + (size_t)c * D) : (ei_p + (size_t)(c - U_N) * D);
    atomicAdd(&aggA[(size_t)slot * D + lane], wi * bi[lane]);
    atomicAdd(&aggB[(size_t)slot * D + lane], wp * bp[lane]);
  }
}

// ---------------------------------------------------------------------------
// One wave per sample: dots for (pos,neg) x (int,pop); out = 0.25*(e+a)·(e+a)
__global__ __launch_bounds__(256) void k_dots(
    const int* __restrict__ user, const int* __restrict__ pos, const int* __restrict__ neg,
    const float* __restrict__ eu_i, const float* __restrict__ ei_i,
    const float* __restrict__ eu_p, const float* __restrict__ ei_p,
    const int* __restrict__ map, const float* __restrict__ aggA, const float* __restrict__ aggB,
    float* __restrict__ dpi, float* __restrict__ dni,
    float* __restrict__ dpp, float* __restrict__ dnp_) {
  int lane = threadIdx.x & 63;
  int b = (blockIdx.x * blockDim.x + threadIdx.x) >> 6;
  if (b >= B) return;
  int u = user[b], p = pos[b], n = neg[b];
  int su = map[u], sp = map[U_N + p], sn = map[U_N + n];
  float oui = eu_i[(size_t)u * D + lane] + aggA[(size_t)su * D + lane];
  float oup = eu_p[(size_t)u * D + lane] + aggB[(size_t)su * D + lane];
  float opi = ei_i[(size_t)p * D + lane] + aggA[(size_t)sp * D + lane];
  float opp = ei_p[(size_t)p * D + lane] + aggB[(size_t)sp * D + lane];
  float oni = ei_i[(size_t)n * D + lane] + aggA[(size_t)sn * D + lane];
  float onp = ei_p[(size_t)n * D + lane] + aggB[(size_t)sn * D + lane];
  float s0 = wave_sum(oui * opi);
  float s1 = wave_sum(oui * oni);
  float s2 = wave_sum(oup * opp);
  float s3 = wave_sum(oup * onp);
  if (lane == 0) {
    dpi[b] = 0.25f * s0;
    dni[b] = 0.25f * s1;
    dpp[b] = 0.25f * s2;
    dnp_[b] = 0.25f * s3;
  }
}

// ---------------------------------------------------------------------------
// Per-sample BPR-style losses; all are means over B. acc[0] += sum/B
__global__ __launch_bounds__(256) void k_bpr(
    const unsigned char* __restrict__ ms8, const unsigned char* __restrict__ mt8,
    const float* __restrict__ dots, const int* __restrict__ det,
    float* __restrict__ acc) {
  int b = blockIdx.x * blockDim.x + threadIdx.x;
  const float* spi = dots;
  const float* sni = dots + B;
  const float* spp = dots + 2 * B;
  const float* snp = dots + 3 * B;
  const float* tpi = dots + 4 * B;
  const float* tni = dots + 5 * B;
  const float* tpp = dots + 6 * B;
  const float* tnp = dots + 7 * B;
  float contrib = 0.f;
  if (b < B) {
    int db = det[0], dc = det[1];
    float ms, mt;
    if (dc > 100) {  // float32 layout
      ms = (((const float*)ms8)[b] != 0.f) ? 1.f : 0.f;
      mt = (((const float*)mt8)[b] != 0.f) ? 1.f : 0.f;
    } else if (db > 100) {  // uint8 (numpy bool) layout
      ms = ms8[b] ? 1.f : 0.f;
      mt = mt8[b] ? 1.f : 0.f;
    } else {  // int32 layout
      ms = ((const int*)ms8)[b] ? 1.f : 0.f;
      mt = ((const int*)mt8)[b] ? 1.f : 0.f;
    }
    float l_int_s = ms * softplus_f(sni[b] - spi[b]);
    float l_pop_s = ms * softplus_f(spp[b] - snp[b]) + (1.f - ms) * softplus_f(snp[b] - spp[b]);
    float l_tot_s = softplus_f((sni[b] + snp[b]) - (spi[b] + spp[b]));
    float l_int_t = mt * softplus_f(tni[b] - tpi[b]);
    float l_pop_t = mt * softplus_f(tpp[b] - tnp[b]) + (1.f - mt) * softplus_f(tnp[b] - tpp[b]);
    float l_tot_t = softplus_f((tni[b] + tnp[b]) - (tpi[b] + tpp[b]));
    contrib = (l_tot_s + l_tot_t + 0.1f * (l_int_s + l_int_t) + 0.1f * (l_pop_s + l_pop_t)) *
              (1.f / (float)B);
  }
#pragma unroll
  for (int off = 32; off; off >>= 1) contrib += __shfl_xor(contrib, off, 64);
  __shared__ float wsum_[4];
  if ((threadIdx.x & 63) == 0) wsum_[threadIdx.x >> 6] = contrib;
  __syncthreads();
  if (threadIdx.x == 0) atomicAdd(&acc[0], wsum_[0] + wsum_[1] + wsum_[2] + wsum_[3]);
}

// ---------------------------------------------------------------------------
// Fused masked-L1 over all three row segments. Register accumulation across
// the grid-stride loop; ONE block-level reduction; 7 atomics per block total.
// acc[1]=num_su, acc[2]=num_si, acc[3]=num_tu, acc[4]=num_ti,
// acc[5]=cnt_u,  acc[6]=cnt_si, acc[7]=cnt_ti
__global__ __launch_bounds__(256) void k_dis_fused(
    const float* __restrict__ su_i, const float* __restrict__ su_p,
    const float* __restrict__ tu_i, const float* __restrict__ tu_p,
    const float* __restrict__ si_i, const float* __restrict__ si_p,
    const float* __restrict__ ti_i, const float* __restrict__ ti_p,
    const int* __restrict__ map_s, const int* __restrict__ map_t,
    float* __restrict__ acc) {
  int lane = threadIdx.x & 63;
  int wave = (blockIdx.x * blockDim.x + threadIdx.x) >> 6;
  int nwaves = (gridDim.x * blockDim.x) >> 6;
  float a1 = 0.f, a2 = 0.f, a3 = 0.f, a4 = 0.f;  // per-lane L1 partials
  float c5 = 0.f, c6 = 0.f, c7 = 0.f;            // row counts (lane 0 only)
  for (int r = wave; r < NROWS_ALL; r += nwaves) {
    if (r < U_N) {
      if (map_s[r] < 0) continue;  // user rows: flagged identically in map_t
      size_t o = (size_t)r * D + lane;
      a1 += fabsf(su_i[o] - su_p[o]);
      a3 += fabsf(tu_i[o] - tu_p[o]);
      if (lane == 0) c5 += 1.f;
    } else if (r < U_N + SI_N) {
      int rr = r - U_N;
      if (map_s[U_N + rr] < 0) continue;
      size_t o = (size_t)rr * D + lane;
      a2 += fabsf(si_i[o] - si_p[o]);
      if (lane == 0) c6 += 1.f;
    } else {
      int rr = r - U_N - SI_N;
      if (map_t[U_N + rr] < 0) continue;
      size_t o = (size_t)rr * D + lane;
      a4 += fabsf(ti_i[o] - ti_p[o]);
      if (lane == 0) c7 += 1.f;
    }
  }
  a1 = wave_sum(a1);
  a2 = wave_sum(a2);
  a3 = wave_sum(a3);
  a4 = wave_sum(a4);
  __shared__ float sb[4][8];
  if (lane == 0) {
    int w = threadIdx.x >> 6;
    sb[w][0] = a1; sb[w][1] = a2; sb[w][2] = a3; sb[w][3] = a4;
    sb[w][4] = c5; sb[w][5] = c6; sb[w][6] = c7;
  }
  __syncthreads();
  int t = threadIdx.x;
  if (t < 7) {
    float v = sb[0][t] + sb[1][t] + sb[2][t] + sb[3][t];
    atomicAdd(&acc[1 + t], v);
  }
}

// ---------------------------------------------------------------------------
__global__ void k_final(const float* __restrict__ acc, float* __restrict__ out) {
  if (threadIdx.x == 0 && blockIdx.x == 0) {
    float cu = fmaxf(acc[5], 1.f);
    float cs = fmaxf(acc[6], 1.f);
    float ct = fmaxf(acc[7], 1.f);
    float dis = acc[1] / (cu * (float)D) + acc[2] / (cs * (float)D) +
                acc[3] / (cu * (float)D) + acc[4] / (ct * (float)D);
    out[0] = acc[0] - 0.01f * dis;
  }
}

// ---------------------------------------------------------------------------
extern "C" void kernel_launch(void* const* d_in, const int* in_sizes, int n_in,
                              void* d_out, int out_size, void* d_ws, size_t ws_size,
                              hipStream_t stream) {
  const int* user = (const int*)d_in[0];
  const int* spos = (const int*)d_in[1];
  const int* sneg = (const int*)d_in[2];
  const int* tpos = (const int*)d_in[3];
  const int* tneg = (const int*)d_in[4];
  const unsigned char* mask_s = (const unsigned char*)d_in[5];
  const unsigned char* mask_t = (const unsigned char*)d_in[6];
  const float* su_int = (const float*)d_in[7];
  const float* si_int = (const float*)d_in[8];
  const float* tu_int = (const float*)d_in[9];
  const float* ti_int = (const float*)d_in[10];
  const float* su_pop = (const float*)d_in[11];
  const float* si_pop = (const float*)d_in[12];
  const float* tu_pop = (const float*)d_in[13];
  const float* ti_pop = (const float*)d_in[14];
  const int* s_rows = (const int*)d_in[15];
  const int* s_cols = (const int*)d_in[16];
  const float* s_vals = (const float*)d_in[17];
  const int* t_rows = (const int*)d_in[18];
  const int* t_cols = (const int*)d_in[19];
  const float* t_vals = (const float*)d_in[20];
  const float* drop_s_int = (const float*)d_in[21];
  const float* drop_t_int = (const float*)d_in[22];
  const float* drop_s_pop = (const float*)d_in[23];
  const float* drop_t_pop = (const float*)d_in[24];
  const int nnz_s = in_sizes[15];
  const int nnz_t = in_sizes[18];

  // Workspace layout (~21 MB)
  float* aggA = (float*)d_ws;                       // SLOTS*D  (int factor)
  float* aggB = aggA + (size_t)SLOTS * D;           // SLOTS*D  (pop factor)
  int* map_s = (int*)(aggB + (size_t)SLOTS * D);    // NS
  int* map_t = map_s + NS;                          // NT
  float* dots = (float*)(map_t + NT);               // 8*B
  float* acc = dots + 8 * B;                        // 16 floats
  int* det = (int*)(acc + 16);                      // 2 ints
  int* cnt = det + 2;                               // SLOTS
  int* ovcnt = cnt + SLOTS;                         // 1
  int* ov = ovcnt + 1;                              // 2*OVCAP
  int* bucket = ov + 2 * OVCAP;                     // SLOTS*CAP

  hipMemsetAsync(acc, 0, 16 * sizeof(float), stream);
  hipMemsetAsync(map_s, 0xFF, (size_t)NS * sizeof(int), stream);   // -1
  hipMemsetAsync(map_t, 0xFF, (size_t)NT * sizeof(int), stream);   // -1
  hipMemsetAsync(cnt, 0, (size_t)(SLOTS + 1) * sizeof(int), stream); // cnt + ovcnt

  k_build_maps<<<(3 * B + 255) / 256, 256, 0, stream>>>(user, spos, sneg, tpos, tneg, map_s, map_t);
  k_detect<<<1, 256, 0, stream>>>(mask_s, B, det);

  // ---- source graph ----
  k_compact<<<(nnz_s + 255) / 256, 256, 0, stream>>>(s_rows, map_s, cnt, bucket, ovcnt, ov, nnz_s);
  k_accum<<<SLOTS / 4, 256, 0, stream>>>(s_cols, s_vals, drop_s_int, drop_s_pop, cnt, bucket,
                                         su_int, si_int, su_pop, si_pop, aggA, aggB);
  k_over<<<1, 256, 0, stream>>>(ovcnt, ov, s_cols, s_vals, drop_s_int, drop_s_pop,
                                su_int, si_int, su_pop, si_pop, aggA, aggB);
  k_dots<<<(B * 64) / 256, 256, 0, stream>>>(user, spos, sneg, su_int, si_int, su_pop, si_pop,
                                             map_s, aggA, aggB,
                                             dots, dots + B, dots + 2 * B, dots + 3 * B);

  // ---- target graph (reuse bucket/cnt/agg buffers) ----
  hipMemsetAsync(cnt, 0, (size_t)(SLOTS + 1) * sizeof(int), stream);
  k_compact<<<(nnz_t + 255) / 256, 256, 0, stream>>>(t_rows, map_t, cnt, bucket, ovcnt, ov, nnz_t);
  k_accum<<<SLOTS / 4, 256, 0, stream>>>(t_cols, t_vals, drop_t_int, drop_t_pop, cnt, bucket,
                                         tu_int, ti_int, tu_pop, ti_pop, aggA, aggB);
  k_over<<<1, 256, 0, stream>>>(ovcnt, ov, t_cols, t_vals, drop_t_int, drop_t_pop,
                                tu_int, ti_int, tu_pop, ti_pop, aggA, aggB);
  k_dots<<<(B * 64) / 256, 256, 0, stream>>>(user, tpos, tneg, tu_int, ti_int, tu_pop, ti_pop,
                                             map_t, aggA, aggB,
                                             dots + 4 * B, dots + 5 * B, dots + 6 * B, dots + 7 * B);

  // ---- losses ----
  k_bpr<<<(B + 255) / 256, 256, 0, stream>>>(mask_s, mask_t, dots, det, acc);
  k_dis_fused<<<256, 256, 0, stream>>>(su_int, su_pop, tu_int, tu_pop,
                                       si_int, si_pop, ti_int, ti_pop,
                                       map_s, map_t, acc);
  k_final<<<1, 64, 0, stream>>>(acc, (float*)d_out);
}

// Round 4
// 508.413 us; speedup vs baseline: 3.9614x; 1.0782x over previous
//
#include <hip/hip_runtime.h>
#include <math.h>

// Problem constants (match reference file)
constexpr int U_N = 100000;
constexpr int SI_N = 50000;
constexpr int TI_N = 40000;
constexpr int D = 64;
constexpr int B = 8192;
constexpr int NS = U_N + SI_N;   // 150000 rows in source graph
constexpr int NT = U_N + TI_N;   // 140000 rows in target graph
constexpr int SLOTS = 3 * B;     // compact agg slots: users | pos items | neg items
constexpr int CAP = 64;          // bucket capacity per slot (Poisson lambda ~21)
constexpr int OVCAP = 4096;      // overflow list capacity (statistically never used)
constexpr int NROWS_ALL = U_N + SI_N + TI_N;  // fused dis-loss row space

__device__ __forceinline__ float wave_sum(float x) {
#pragma unroll
  for (int m = 32; m; m >>= 1) x += __shfl_xor(x, m, 64);
  return x;
}

// softplus(z) = log(1+e^z), numerically stable
__device__ __forceinline__ float softplus_f(float z) {
  return fmaxf(z, 0.f) + log1pf(expf(-fabsf(z)));
}

// ---------------------------------------------------------------------------
// Fused: blocks 0..95 build row->slot maps; block 96 classifies mask layout.
__global__ __launch_bounds__(256) void k_init(
    const int* __restrict__ user, const int* __restrict__ spos, const int* __restrict__ sneg,
    const int* __restrict__ tpos, const int* __restrict__ tneg,
    int* __restrict__ map_s, int* __restrict__ map_t,
    const unsigned char* __restrict__ m, int* __restrict__ det) {
  if (blockIdx.x < 96) {
    int t = blockIdx.x * blockDim.x + threadIdx.x;  // < 3*B exactly
    if (t < B) {
      int u = user[t];
      map_s[u] = t;
      map_t[u] = t;
    } else if (t < 2 * B) {
      int b = t - B;
      map_s[U_N + spos[b]] = t;
      map_t[U_N + tpos[b]] = t;
    } else {
      int b = t - 2 * B;
      map_s[U_N + sneg[b]] = t;
      map_t[U_N + tneg[b]] = t;
    }
    return;
  }
  // ---- mask layout detect (one block) ----
  int t = threadIdx.x;
  int cb = 0, cc = 0;
  for (int i = t; i < B; i += 256) {
    unsigned char v = m[i];
    if ((i & 3) && v) cb++;
    if (v > 1) cc++;
  }
#pragma unroll
  for (int off = 32; off; off >>= 1) {
    cb += __shfl_xor(cb, off, 64);
    cc += __shfl_xor(cc, off, 64);
  }
  __shared__ int sb[4], sc[4];
  if ((t & 63) == 0) { sb[t >> 6] = cb; sc[t >> 6] = cc; }
  __syncthreads();
  if (t == 0) {
    det[0] = sb[0] + sb[1] + sb[2] + sb[3];
    det[1] = sc[0] + sc[1] + sc[2] + sc[3];
  }
}

// ---------------------------------------------------------------------------
// Phase A (both graphs): one THREAD per edge. Filter by map; append surviving
// edge ids into per-slot buckets. Overflow (p~0) goes to a small list.
__global__ __launch_bounds__(256) void k_compact2(
    const int* __restrict__ s_rows, const int* __restrict__ t_rows,
    const int* __restrict__ map_s, const int* __restrict__ map_t,
    int* __restrict__ cnt_s, int* __restrict__ cnt_t,
    int* __restrict__ bucket_s, int* __restrict__ bucket_t,
    int* __restrict__ ovcnt_s, int* __restrict__ ovcnt_t,
    int* __restrict__ ov_s, int* __restrict__ ov_t, int nnz_s, int nnz_t) {
  int e = blockIdx.x * 256 + threadIdx.x;
  const int* rows;
  const int* map;
  int* cnt;
  int* bucket;
  int* ovcnt;
  int* ov;
  if (e < nnz_s) {
    rows = s_rows; map = map_s; cnt = cnt_s; bucket = bucket_s; ovcnt = ovcnt_s; ov = ov_s;
  } else {
    e -= nnz_s;
    if (e >= nnz_t) return;
    rows = t_rows; map = map_t; cnt = cnt_t; bucket = bucket_t; ovcnt = ovcnt_t; ov = ov_t;
  }
  int slot = map[rows[e]];
  if (slot < 0) return;
  int pos = atomicAdd(&cnt[slot], 1);
  if (pos < CAP) {
    bucket[slot * CAP + pos] = e;
  } else {
    int o = atomicAdd(ovcnt, 1);
    if (o < OVCAP) { ov[2 * o] = slot; ov[2 * o + 1] = e; }
  }
}

// ---------------------------------------------------------------------------
// Phase B: one WAVE per slot. Lane layout: group g=lane>>4 handles edge k+g,
// sub=lane&15 handles dims [4*sub, 4*sub+4). Each wave-load instruction
// fetches 4 edge-rows (float4/lane); x2 manual unroll = 4 loads in flight.
// Cross-group shfl_xor reduce at the end; quarter-wave float4 store.
// Overflow entries (normally none) are applied by the owning wave: race-free.
__global__ __launch_bounds__(256) void k_accum(
    const int* __restrict__ cols, const float* __restrict__ vals,
    const float* __restrict__ di, const float* __restrict__ dp,
    const int* __restrict__ cnt, const int* __restrict__ bucket,
    const int* __restrict__ ovcnt, const int* __restrict__ ov,
    const float* __restrict__ eu_i, const float* __restrict__ ei_i,
    const float* __restrict__ eu_p, const float* __restrict__ ei_p,
    float* __restrict__ aggA, float* __restrict__ aggB) {
  int lane = threadIdx.x & 63;
  int s = (blockIdx.x * 256 + threadIdx.x) >> 6;
  if (s >= SLOTS) return;
  int m = min(cnt[s], CAP);
  int g = lane >> 4, sub = lane & 15;
  int c = 0;
  float wi = 0.f, wp = 0.f;
  if (lane < m) {
    int e = bucket[s * CAP + lane];
    c = cols[e];
    float v = vals[e];
    wi = v * di[e];
    wp = v * dp[e];
  }
  float aIx = 0, aIy = 0, aIz = 0, aIw = 0;
  float aPx = 0, aPy = 0, aPz = 0, aPw = 0;
  for (int k = 0; k < m; k += 8) {
    int i0 = k + g, i1 = k + 4 + g;                  // <= 63 always
    int c0 = __shfl(c, i0, 64), c1 = __shfl(c, i1, 64);
    float wi0 = __shfl(wi, i0, 64), wi1 = __shfl(wi, i1, 64);
    float wp0 = __shfl(wp, i0, 64), wp1 = __shfl(wp, i1, 64);
    const float* bi0 = (c0 < U_N) ? (eu_i + (size_t)c0 * D) : (ei_i + (size_t)(c0 - U_N) * D);
    const float* bp0 = (c0 < U_N) ? (eu_p + (size_t)c0 * D) : (ei_p + (size_t)(c0 - U_N) * D);
    const float* bi1 = (c1 < U_N) ? (eu_i + (size_t)c1 * D) : (ei_i + (size_t)(c1 - U_N) * D);
    const float* bp1 = (c1 < U_N) ? (eu_p + (size_t)c1 * D) : (ei_p + (size_t)(c1 - U_N) * D);
    float4 vI0 = *(const float4*)(bi0 + 4 * sub);
    float4 vP0 = *(const float4*)(bp0 + 4 * sub);
    float4 vI1 = *(const float4*)(bi1 + 4 * sub);
    float4 vP1 = *(const float4*)(bp1 + 4 * sub);
    aIx = fmaf(wi0, vI0.x, aIx); aIy = fmaf(wi0, vI0.y, aIy);
    aIz = fmaf(wi0, vI0.z, aIz); aIw = fmaf(wi0, vI0.w, aIw);
    aPx = fmaf(wp0, vP0.x, aPx); aPy = fmaf(wp0, vP0.y, aPy);
    aPz = fmaf(wp0, vP0.z, aPz); aPw = fmaf(wp0, vP0.w, aPw);
    aIx = fmaf(wi1, vI1.x, aIx); aIy = fmaf(wi1, vI1.y, aIy);
    aIz = fmaf(wi1, vI1.z, aIz); aIw = fmaf(wi1, vI1.w, aIw);
    aPx = fmaf(wp1, vP1.x, aPx); aPy = fmaf(wp1, vP1.y, aPy);
    aPz = fmaf(wp1, vP1.z, aPz); aPw = fmaf(wp1, vP1.w, aPw);
  }
  // cross-group reduce: lanes {sub, sub+16, sub+32, sub+48} hold same dims
#define XRED(x) x += __shfl_xor(x, 16, 64); x += __shfl_xor(x, 32, 64);
  XRED(aIx) XRED(aIy) XRED(aIz) XRED(aIw)
  XRED(aPx) XRED(aPy) XRED(aPz) XRED(aPw)
#undef XRED
  // overflow fixup by owner wave (normally nov==0)
  int nov = min(*ovcnt, OVCAP);
  for (int i = 0; i < nov; ++i) {
    if (ov[2 * i] == s) {
      int e = ov[2 * i + 1];
      int cc = cols[e];
      float v = vals[e];
      float wwi = v * di[e], wwp = v * dp[e];
      const float* bi = (cc < U_N) ? (eu_i + (size_t)cc * D) : (ei_i + (size_t)(cc - U_N) * D);
      const float* bp = (cc < U_N) ? (eu_p + (size_t)cc * D) : (ei_p + (size_t)(cc - U_N) * D);
      if (lane < 16) {
        float4 vI = *(const float4*)(bi + 4 * sub);
        float4 vP = *(const float4*)(bp + 4 * sub);
        aIx = fmaf(wwi, vI.x, aIx); aIy = fmaf(wwi, vI.y, aIy);
        aIz = fmaf(wwi, vI.z, aIz); aIw = fmaf(wwi, vI.w, aIw);
        aPx = fmaf(wwp, vP.x, aPx); aPy = fmaf(wwp, vP.y, aPy);
        aPz = fmaf(wwp, vP.z, aPz); aPw = fmaf(wwp, vP.w, aPw);
      }
    }
  }
  if (lane < 16) {
    *(float4*)(aggA + (size_t)s * D + 4 * sub) = make_float4(aIx, aIy, aIz, aIw);
    *(float4*)(aggB + (size_t)s * D + 4 * sub) = make_float4(aPx, aPy, aPz, aPw);
  }
}

// ---------------------------------------------------------------------------
// One wave per sample for ONE graph (selected by pointers). dst: 4 arrays of B.
__global__ __launch_bounds__(256) void k_dots(
    const int* __restrict__ user, const int* __restrict__ pos, const int* __restrict__ neg,
    const float* __restrict__ eu_i, const float* __restrict__ ei_i,
    const float* __restrict__ eu_p, const float* __restrict__ ei_p,
    const int* __restrict__ map, const float* __restrict__ aggA, const float* __restrict__ aggB,
    float* __restrict__ dst) {
  int lane = threadIdx.x & 63;
  int b = (blockIdx.x * blockDim.x + threadIdx.x) >> 6;
  if (b >= B) return;
  int u = user[b], p = pos[b], n = neg[b];
  int su = map[u], sp = map[U_N + p], sn = map[U_N + n];
  float oui = eu_i[(size_t)u * D + lane] + aggA[(size_t)su * D + lane];
  float oup = eu_p[(size_t)u * D + lane] + aggB[(size_t)su * D + lane];
  float opi = ei_i[(size_t)p * D + lane] + aggA[(size_t)sp * D + lane];
  float opp = ei_p[(size_t)p * D + lane] + aggB[(size_t)sp * D + lane];
  float oni = ei_i[(size_t)n * D + lane] + aggA[(size_t)sn * D + lane];
  float onp = ei_p[(size_t)n * D + lane] + aggB[(size_t)sn * D + lane];
  float s0 = wave_sum(oui * opi);
  float s1 = wave_sum(oui * oni);
  float s2 = wave_sum(oup * opp);
  float s3 = wave_sum(oup * onp);
  if (lane == 0) {
    dst[b] = 0.25f * s0;
    dst[B + b] = 0.25f * s1;
    dst[2 * B + b] = 0.25f * s2;
    dst[3 * B + b] = 0.25f * s3;
  }
}

// ---------------------------------------------------------------------------
// Per-sample BPR-style losses; all are means over B. acc[0] += sum/B
__global__ __launch_bounds__(256) void k_bpr(
    const unsigned char* __restrict__ ms8, const unsigned char* __restrict__ mt8,
    const float* __restrict__ dots, const int* __restrict__ det,
    float* __restrict__ acc) {
  int b = blockIdx.x * blockDim.x + threadIdx.x;
  const float* spi = dots;
  const float* sni = dots + B;
  const float* spp = dots + 2 * B;
  const float* snp = dots + 3 * B;
  const float* tpi = dots + 4 * B;
  const float* tni = dots + 5 * B;
  const float* tpp = dots + 6 * B;
  const float* tnp = dots + 7 * B;
  float contrib = 0.f;
  if (b < B) {
    int db = det[0], dc = det[1];
    float ms, mt;
    if (dc > 100) {  // float32 layout
      ms = (((const float*)ms8)[b] != 0.f) ? 1.f : 0.f;
      mt = (((const float*)mt8)[b] != 0.f) ? 1.f : 0.f;
    } else if (db > 100) {  // uint8 (numpy bool) layout
      ms = ms8[b] ? 1.f : 0.f;
      mt = mt8[b] ? 1.f : 0.f;
    } else {  // int32 layout
      ms = ((const int*)ms8)[b] ? 1.f : 0.f;
      mt = ((const int*)mt8)[b] ? 1.f : 0.f;
    }
    float l_int_s = ms * softplus_f(sni[b] - spi[b]);
    float l_pop_s = ms * softplus_f(spp[b] - snp[b]) + (1.f - ms) * softplus_f(snp[b] - spp[b]);
    float l_tot_s = softplus_f((sni[b] + snp[b]) - (spi[b] + spp[b]));
    float l_int_t = mt * softplus_f(tni[b] - tpi[b]);
    float l_pop_t = mt * softplus_f(tpp[b] - tnp[b]) + (1.f - mt) * softplus_f(tnp[b] - tpp[b]);
    float l_tot_t = softplus_f((tni[b] + tnp[b]) - (tpi[b] + tpp[b]));
    contrib = (l_tot_s + l_tot_t + 0.1f * (l_int_s + l_int_t) + 0.1f * (l_pop_s + l_pop_t)) *
              (1.f / (float)B);
  }
#pragma unroll
  for (int off = 32; off; off >>= 1) contrib += __shfl_xor(contrib, off, 64);
  __shared__ float wsum_[4];
  if ((threadIdx.x & 63) == 0) wsum_[threadIdx.x >> 6] = contrib;
  __syncthreads();
  if (threadIdx.x == 0) atomicAdd(&acc[0], wsum_[0] + wsum_[1] + wsum_[2] + wsum_[3]);
}

// ---------------------------------------------------------------------------
// Fused masked-L1 over all three row segments; register accumulation,
// one block reduction, 7 atomics per block.
__global__ __launch_bounds__(256) void k_dis_fused(
    const float* __restrict__ su_i, const float* __restrict__ su_p,
    const float* __restrict__ tu_i, const float* __restrict__ tu_p,
    const float* __restrict__ si_i, const float* __restrict__ si_p,
    const float* __restrict__ ti_i, const float* __restrict__ ti_p,
    const int* __restrict__ map_s, const int* __restrict__ map_t,
    float* __restrict__ acc) {
  int lane = threadIdx.x & 63;
  int wave = (blockIdx.x * blockDim.x + threadIdx.x) >> 6;
  int nwaves = (gridDim.x * blockDim.x) >> 6;
  float a1 = 0.f, a2 = 0.f, a3 = 0.f, a4 = 0.f;  // per-lane L1 partials
  float c5 = 0.f, c6 = 0.f, c7 = 0.f;            // row counts (lane 0 only)
  for (int r = wave; r < NROWS_ALL; r += nwaves) {
    if (r < U_N) {
      if (map_s[r] < 0) continue;
      size_t o = (size_t)r * D + lane;
      a1 += fabsf(su_i[o] - su_p[o]);
      a3 += fabsf(tu_i[o] - tu_p[o]);
      if (lane == 0) c5 += 1.f;
    } else if (r < U_N + SI_N) {
      int rr = r - U_N;
      if (map_s[U_N + rr] < 0) continue;
      size_t o = (size_t)rr * D + lane;
      a2 += fabsf(si_i[o] - si_p[o]);
      if (lane == 0) c6 += 1.f;
    } else {
      int rr = r - U_N - SI_N;
      if (map_t[U_N + rr] < 0) continue;
      size_t o = (size_t)rr * D + lane;
      a4 += fabsf(ti_i[o] - ti_p[o]);
      if (lane == 0) c7 += 1.f;
    }
  }
  a1 = wave_sum(a1);
  a2 = wave_sum(a2);
  a3 = wave_sum(a3);
  a4 = wave_sum(a4);
  __shared__ float sb[4][8];
  if (lane == 0) {
    int w = threadIdx.x >> 6;
    sb[w][0] = a1; sb[w][1] = a2; sb[w][2] = a3; sb[w][3] = a4;
    sb[w][4] = c5; sb[w][5] = c6; sb[w][6] = c7;
  }
  __syncthreads();
  int t = threadIdx.x;
  if (t < 7) {
    float v = sb[0][t] + sb[1][t] + sb[2][t] + sb[3][t];
    atomicAdd(&acc[1 + t], v);
  }
}

// ---------------------------------------------------------------------------
__global__ void k_final(const float* __restrict__ acc, float* __restrict__ out) {
  if (threadIdx.x == 0 && blockIdx.x == 0) {
    float cu = fmaxf(acc[5], 1.f);
    float cs = fmaxf(acc[6], 1.f);
    float ct = fmaxf(acc[7], 1.f);
    float dis = acc[1] / (cu * (float)D) + acc[2] / (cs * (float)D) +
                acc[3] / (cu * (float)D) + acc[4] / (ct * (float)D);
    out[0] = acc[0] - 0.01f * dis;
  }
}

// ---------------------------------------------------------------------------
extern "C" void kernel_launch(void* const* d_in, const int* in_sizes, int n_in,
                              void* d_out, int out_size, void* d_ws, size_t ws_size,
                              hipStream_t stream) {
  const int* user = (const int*)d_in[0];
  const int* spos = (const int*)d_in[1];
  const int* sneg = (const int*)d_in[2];
  const int* tpos = (const int*)d_in[3];
  const int* tneg = (const int*)d_in[4];
  const unsigned char* mask_s = (const unsigned char*)d_in[5];
  const unsigned char* mask_t = (const unsigned char*)d_in[6];
  const float* su_int = (const float*)d_in[7];
  const float* si_int = (const float*)d_in[8];
  const float* tu_int = (const float*)d_in[9];
  const float* ti_int = (const float*)d_in[10];
  const float* su_pop = (const float*)d_in[11];
  const float* si_pop = (const float*)d_in[12];
  const float* tu_pop = (const float*)d_in[13];
  const float* ti_pop = (const float*)d_in[14];
  const int* s_rows = (const int*)d_in[15];
  const int* s_cols = (const int*)d_in[16];
  const float* s_vals = (const float*)d_in[17];
  const int* t_rows = (const int*)d_in[18];
  const int* t_cols = (const int*)d_in[19];
  const float* t_vals = (const float*)d_in[20];
  const float* drop_s_int = (const float*)d_in[21];
  const float* drop_t_int = (const float*)d_in[22];
  const float* drop_s_pop = (const float*)d_in[23];
  const float* drop_t_pop = (const float*)d_in[24];
  const int nnz_s = in_sizes[15];
  const int nnz_t = in_sizes[18];

  // Workspace layout (~27 MB)
  float* aggA = (float*)d_ws;                       // SLOTS*D (int factor, reused s->t)
  float* aggB = aggA + (size_t)SLOTS * D;           // SLOTS*D (pop factor)
  float* acc = aggB + (size_t)SLOTS * D;            // 16 floats
  int* det = (int*)(acc + 16);                      // 2
  int* ovcnt_s = det + 2;                           // 1
  int* ovcnt_t = ovcnt_s + 1;                       // 1
  int* cnt_s = ovcnt_t + 1;                         // SLOTS
  int* cnt_t = cnt_s + SLOTS;                       // SLOTS
  int* map_s = cnt_t + SLOTS;                       // NS
  int* map_t = map_s + NS;                          // NT
  float* dots = (float*)(map_t + NT);               // 8*B
  int* ov_s = (int*)(dots + 8 * B);                 // 2*OVCAP
  int* ov_t = ov_s + 2 * OVCAP;                     // 2*OVCAP
  int* bucket_s = ov_t + 2 * OVCAP;                 // SLOTS*CAP
  int* bucket_t = bucket_s + SLOTS * CAP;           // SLOTS*CAP

  // acc..cnt_t contiguous: one zero-memset; maps contiguous: one 0xFF memset
  hipMemsetAsync(acc, 0, (size_t)(16 + 2 + 2 + 2 * SLOTS) * sizeof(int), stream);
  hipMemsetAsync(map_s, 0xFF, (size_t)(NS + NT) * sizeof(int), stream);

  k_init<<<97, 256, 0, stream>>>(user, spos, sneg, tpos, tneg, map_s, map_t, mask_s, det);

  k_compact2<<<(nnz_s + nnz_t + 255) / 256, 256, 0, stream>>>(
      s_rows, t_rows, map_s, map_t, cnt_s, cnt_t, bucket_s, bucket_t,
      ovcnt_s, ovcnt_t, ov_s, ov_t, nnz_s, nnz_t);

  // ---- source graph ----
  k_accum<<<SLOTS / 4, 256, 0, stream>>>(s_cols, s_vals, drop_s_int, drop_s_pop,
                                         cnt_s, bucket_s, ovcnt_s, ov_s,
                                         su_int, si_int, su_pop, si_pop, aggA, aggB);
  k_dots<<<(B * 64) / 256, 256, 0, stream>>>(user, spos, sneg, su_int, si_int, su_pop, si_pop,
                                             map_s, aggA, aggB, dots);

  // ---- target graph (reuse agg buffers) ----
  k_accum<<<SLOTS / 4, 256, 0, stream>>>(t_cols, t_vals, drop_t_int, drop_t_pop,
                                         cnt_t, bucket_t, ovcnt_t, ov_t,
                                         tu_int, ti_int, tu_pop, ti_pop, aggA, aggB);
  k_dots<<<(B * 64) / 256, 256, 0, stream>>>(user, tpos, tneg, tu_int, ti_int, tu_pop, ti_pop,
                                             map_t, aggA, aggB, dots + 4 * B);

  // ---- losses ----
  k_bpr<<<(B + 255) / 256, 256, 0, stream>>>(mask_s, mask_t, dots, det, acc);
  k_dis_fused<<<256, 256, 0, stream>>>(su_int, su_pop, tu_int, tu_pop,
                                       si_int, si_pop, ti_int, ti_pop,
                                       map_s, map_t, acc);
  k_final<<<1, 64, 0, stream>>>(acc, (float*)d_out);
}

// Round 5
// 490.999 us; speedup vs baseline: 4.1019x; 1.0355x over previous
//
#include <hip/hip_runtime.h>
#include <math.h>

// Problem constants (match reference file)
constexpr int U_N = 100000;
constexpr int SI_N = 50000;
constexpr int TI_N = 40000;
constexpr int D = 64;
constexpr int B = 8192;
constexpr int NS = U_N + SI_N;   // 150000 rows in source graph
constexpr int NT = U_N + TI_N;   // 140000 rows in target graph
constexpr int SLOTS = 3 * B;     // compact agg slots: users | pos items | neg items
constexpr int CAP = 64;          // bucket capacity per slot (Poisson lambda ~21)
constexpr int OVCAP = 4096;      // overflow list capacity (statistically never used)
constexpr int NROWS_ALL = U_N + SI_N + TI_N;  // fused dis-loss row space

__device__ __forceinline__ float wave_sum(float x) {
#pragma unroll
  for (int m = 32; m; m >>= 1) x += __shfl_xor(x, m, 64);
  return x;
}

__device__ __forceinline__ float softplus_f(float z) {
  return fmaxf(z, 0.f) + log1pf(expf(-fabsf(z)));
}

// ---------------------------------------------------------------------------
// Fused: blocks 0..95 build row->slot maps; block 96 classifies mask layout.
__global__ __launch_bounds__(256) void k_init(
    const int* __restrict__ user, const int* __restrict__ spos, const int* __restrict__ sneg,
    const int* __restrict__ tpos, const int* __restrict__ tneg,
    int* __restrict__ map_s, int* __restrict__ map_t,
    const unsigned char* __restrict__ m, int* __restrict__ det) {
  if (blockIdx.x < 96) {
    int t = blockIdx.x * blockDim.x + threadIdx.x;  // < 3*B exactly
    if (t < B) {
      int u = user[t];
      map_s[u] = t;
      map_t[u] = t;
    } else if (t < 2 * B) {
      int b = t - B;
      map_s[U_N + spos[b]] = t;
      map_t[U_N + tpos[b]] = t;
    } else {
      int b = t - 2 * B;
      map_s[U_N + sneg[b]] = t;
      map_t[U_N + tneg[b]] = t;
    }
    return;
  }
  int t = threadIdx.x;
  int cb = 0, cc = 0;
  for (int i = t; i < B; i += 256) {
    unsigned char v = m[i];
    if ((i & 3) && v) cb++;
    if (v > 1) cc++;
  }
#pragma unroll
  for (int off = 32; off; off >>= 1) {
    cb += __shfl_xor(cb, off, 64);
    cc += __shfl_xor(cc, off, 64);
  }
  __shared__ int sb[4], sc[4];
  if ((t & 63) == 0) { sb[t >> 6] = cb; sc[t >> 6] = cc; }
  __syncthreads();
  if (t == 0) {
    det[0] = sb[0] + sb[1] + sb[2] + sb[3];
    det[1] = sc[0] + sc[1] + sc[2] + sc[3];
  }
}

// ---------------------------------------------------------------------------
// Phase A (both graphs): one THREAD per edge; filter by map; bucket-append.
__global__ __launch_bounds__(256) void k_compact2(
    const int* __restrict__ s_rows, const int* __restrict__ t_rows,
    const int* __restrict__ map_s, const int* __restrict__ map_t,
    int* __restrict__ cnt_s, int* __restrict__ cnt_t,
    int* __restrict__ bucket_s, int* __restrict__ bucket_t,
    int* __restrict__ ovcnt_s, int* __restrict__ ovcnt_t,
    int* __restrict__ ov_s, int* __restrict__ ov_t, int nnz_s, int nnz_t) {
  int e = blockIdx.x * 256 + threadIdx.x;
  const int* rows;
  const int* map;
  int* cnt;
  int* bucket;
  int* ovcnt;
  int* ov;
  if (e < nnz_s) {
    rows = s_rows; map = map_s; cnt = cnt_s; bucket = bucket_s; ovcnt = ovcnt_s; ov = ov_s;
  } else {
    e -= nnz_s;
    if (e >= nnz_t) return;
    rows = t_rows; map = map_t; cnt = cnt_t; bucket = bucket_t; ovcnt = ovcnt_t; ov = ov_t;
  }
  int slot = map[rows[e]];
  if (slot < 0) return;
  int pos = atomicAdd(&cnt[slot], 1);
  if (pos < CAP) {
    bucket[slot * CAP + pos] = e;
  } else {
    int o = atomicAdd(ovcnt, 1);
    if (o < OVCAP) { ov[2 * o] = slot; ov[2 * o + 1] = e; }
  }
}

// ---------------------------------------------------------------------------
// Accum body shared by both variants. Lane layout: group g=lane>>4 handles
// edges k+g, k+4+g, k+8+g, k+12+g; sub=lane&15 handles dims [4sub,4sub+4).
// 8 independent float4 loads in flight per iteration (16 edges x 2 factors).
__device__ __forceinline__ void accum_slot(
    int s, int lane,
    const int* __restrict__ cols, const float* __restrict__ vals,
    const float* __restrict__ di, const float* __restrict__ dp,
    const int* __restrict__ cnt, const int* __restrict__ bucket,
    const int* __restrict__ ovcnt, const int* __restrict__ ov,
    const float* __restrict__ eu_i, const float* __restrict__ ei_i,
    const float* __restrict__ eu_p, const float* __restrict__ ei_p,
    float* __restrict__ aggA, float* __restrict__ aggB) {
  int m = min(cnt[s], CAP);
  int g = lane >> 4, sub = lane & 15;
  int c = 0;
  float wi = 0.f, wp = 0.f;
  if (lane < m) {
    int e = bucket[s * CAP + lane];
    c = cols[e];
    float v = vals[e];
    wi = v * di[e];
    wp = v * dp[e];
  }
  float aIx = 0, aIy = 0, aIz = 0, aIw = 0;
  float aPx = 0, aPy = 0, aPz = 0, aPw = 0;
  for (int k = 0; k < m; k += 16) {
    int i0 = k + g, i1 = k + 4 + g, i2 = k + 8 + g, i3 = k + 12 + g;  // <= 63
    int c0 = __shfl(c, i0, 64), c1 = __shfl(c, i1, 64);
    int c2 = __shfl(c, i2, 64), c3 = __shfl(c, i3, 64);
    float wi0 = __shfl(wi, i0, 64), wi1 = __shfl(wi, i1, 64);
    float wi2 = __shfl(wi, i2, 64), wi3 = __shfl(wi, i3, 64);
    float wp0 = __shfl(wp, i0, 64), wp1 = __shfl(wp, i1, 64);
    float wp2 = __shfl(wp, i2, 64), wp3 = __shfl(wp, i3, 64);
    const float* bi0 = (c0 < U_N) ? (eu_i + (size_t)c0 * D) : (ei_i + (size_t)(c0 - U_N) * D);
    const float* bi1 = (c1 < U_N) ? (eu_i + (size_t)c1 * D) : (ei_i + (size_t)(c1 - U_N) * D);
    const float* bi2 = (c2 < U_N) ? (eu_i + (size_t)c2 * D) : (ei_i + (size_t)(c2 - U_N) * D);
    const float* bi3 = (c3 < U_N) ? (eu_i + (size_t)c3 * D) : (ei_i + (size_t)(c3 - U_N) * D);
    const float* bp0 = (c0 < U_N) ? (eu_p + (size_t)c0 * D) : (ei_p + (size_t)(c0 - U_N) * D);
    const float* bp1 = (c1 < U_N) ? (eu_p + (size_t)c1 * D) : (ei_p + (size_t)(c1 - U_N) * D);
    const float* bp2 = (c2 < U_N) ? (eu_p + (size_t)c2 * D) : (ei_p + (size_t)(c2 - U_N) * D);
    const float* bp3 = (c3 < U_N) ? (eu_p + (size_t)c3 * D) : (ei_p + (size_t)(c3 - U_N) * D);
    float4 vI0 = *(const float4*)(bi0 + 4 * sub);
    float4 vI1 = *(const float4*)(bi1 + 4 * sub);
    float4 vI2 = *(const float4*)(bi2 + 4 * sub);
    float4 vI3 = *(const float4*)(bi3 + 4 * sub);
    float4 vP0 = *(const float4*)(bp0 + 4 * sub);
    float4 vP1 = *(const float4*)(bp1 + 4 * sub);
    float4 vP2 = *(const float4*)(bp2 + 4 * sub);
    float4 vP3 = *(const float4*)(bp3 + 4 * sub);
    aIx = fmaf(wi0, vI0.x, aIx); aIy = fmaf(wi0, vI0.y, aIy);
    aIz = fmaf(wi0, vI0.z, aIz); aIw = fmaf(wi0, vI0.w, aIw);
    aIx = fmaf(wi1, vI1.x, aIx); aIy = fmaf(wi1, vI1.y, aIy);
    aIz = fmaf(wi1, vI1.z, aIz); aIw = fmaf(wi1, vI1.w, aIw);
    aIx = fmaf(wi2, vI2.x, aIx); aIy = fmaf(wi2, vI2.y, aIy);
    aIz = fmaf(wi2, vI2.z, aIz); aIw = fmaf(wi2, vI2.w, aIw);
    aIx = fmaf(wi3, vI3.x, aIx); aIy = fmaf(wi3, vI3.y, aIy);
    aIz = fmaf(wi3, vI3.z, aIz); aIw = fmaf(wi3, vI3.w, aIw);
    aPx = fmaf(wp0, vP0.x, aPx); aPy = fmaf(wp0, vP0.y, aPy);
    aPz = fmaf(wp0, vP0.z, aPz); aPw = fmaf(wp0, vP0.w, aPw);
    aPx = fmaf(wp1, vP1.x, aPx); aPy = fmaf(wp1, vP1.y, aPy);
    aPz = fmaf(wp1, vP1.z, aPz); aPw = fmaf(wp1, vP1.w, aPw);
    aPx = fmaf(wp2, vP2.x, aPx); aPy = fmaf(wp2, vP2.y, aPy);
    aPz = fmaf(wp2, vP2.z, aPz); aPw = fmaf(wp2, vP2.w, aPw);
    aPx = fmaf(wp3, vP3.x, aPx); aPy = fmaf(wp3, vP3.y, aPy);
    aPz = fmaf(wp3, vP3.z, aPz); aPw = fmaf(wp3, vP3.w, aPw);
  }
#define XRED(x) x += __shfl_xor(x, 16, 64); x += __shfl_xor(x, 32, 64);
  XRED(aIx) XRED(aIy) XRED(aIz) XRED(aIw)
  XRED(aPx) XRED(aPy) XRED(aPz) XRED(aPw)
#undef XRED
  // overflow fixup by owner wave (normally nov==0)
  int nov = min(*ovcnt, OVCAP);
  for (int i = 0; i < nov; ++i) {
    if (ov[2 * i] == s) {
      int e = ov[2 * i + 1];
      int cc = cols[e];
      float v = vals[e];
      float wwi = v * di[e], wwp = v * dp[e];
      const float* bi = (cc < U_N) ? (eu_i + (size_t)cc * D) : (ei_i + (size_t)(cc - U_N) * D);
      const float* bp = (cc < U_N) ? (eu_p + (size_t)cc * D) : (ei_p + (size_t)(cc - U_N) * D);
      if (lane < 16) {
        float4 vI = *(const float4*)(bi + 4 * sub);
        float4 vP = *(const float4*)(bp + 4 * sub);
        aIx = fmaf(wwi, vI.x, aIx); aIy = fmaf(wwi, vI.y, aIy);
        aIz = fmaf(wwi, vI.z, aIz); aIw = fmaf(wwi, vI.w, aIw);
        aPx = fmaf(wwp, vP.x, aPx); aPy = fmaf(wwp, vP.y, aPy);
        aPz = fmaf(wwp, vP.z, aPz); aPw = fmaf(wwp, vP.w, aPw);
      }
    }
  }
  if (lane < 16) {
    *(float4*)(aggA + (size_t)s * D + 4 * sub) = make_float4(aIx, aIy, aIz, aIw);
    *(float4*)(aggB + (size_t)s * D + 4 * sub) = make_float4(aPx, aPy, aPz, aPw);
  }
}

// Both graphs in one dispatch (big-ws path): sg<SLOTS source, else target.
__global__ __launch_bounds__(256) void k_accum_pair(
    const int* __restrict__ s_cols, const float* __restrict__ s_vals,
    const float* __restrict__ dsi, const float* __restrict__ dsp,
    const int* __restrict__ t_cols, const float* __restrict__ t_vals,
    const float* __restrict__ dti, const float* __restrict__ dtp,
    const int* __restrict__ cnt_s, const int* __restrict__ bucket_s,
    const int* __restrict__ ovcnt_s, const int* __restrict__ ov_s,
    const int* __restrict__ cnt_t, const int* __restrict__ bucket_t,
    const int* __restrict__ ovcnt_t, const int* __restrict__ ov_t,
    const float* __restrict__ su_i, const float* __restrict__ si_i,
    const float* __restrict__ su_p, const float* __restrict__ si_p,
    const float* __restrict__ tu_i, const float* __restrict__ ti_i,
    const float* __restrict__ tu_p, const float* __restrict__ ti_p,
    float* __restrict__ aggSA, float* __restrict__ aggSB,
    float* __restrict__ aggTA, float* __restrict__ aggTB) {
  int lane = threadIdx.x & 63;
  int sg = (blockIdx.x * 256 + threadIdx.x) >> 6;
  if (sg >= 2 * SLOTS) return;
  if (sg < SLOTS) {
    accum_slot(sg, lane, s_cols, s_vals, dsi, dsp, cnt_s, bucket_s, ovcnt_s, ov_s,
               su_i, si_i, su_p, si_p, aggSA, aggSB);
  } else {
    accum_slot(sg - SLOTS, lane, t_cols, t_vals, dti, dtp, cnt_t, bucket_t, ovcnt_t, ov_t,
               tu_i, ti_i, tu_p, ti_p, aggTA, aggTB);
  }
}

// Single-graph variant (fallback path, shared agg buffers).
__global__ __launch_bounds__(256) void k_accum1(
    const int* __restrict__ cols, const float* __restrict__ vals,
    const float* __restrict__ di, const float* __restrict__ dp,
    const int* __restrict__ cnt, const int* __restrict__ bucket,
    const int* __restrict__ ovcnt, const int* __restrict__ ov,
    const float* __restrict__ eu_i, const float* __restrict__ ei_i,
    const float* __restrict__ eu_p, const float* __restrict__ ei_p,
    float* __restrict__ aggA, float* __restrict__ aggB) {
  int lane = threadIdx.x & 63;
  int s = (blockIdx.x * 256 + threadIdx.x) >> 6;
  if (s >= SLOTS) return;
  accum_slot(s, lane, cols, vals, di, dp, cnt, bucket, ovcnt, ov,
             eu_i, ei_i, eu_p, ei_p, aggA, aggB);
}

// ---------------------------------------------------------------------------
__device__ __forceinline__ void dots_one(
    int b, int lane,
    const int* __restrict__ user, const int* __restrict__ pos, const int* __restrict__ neg,
    const float* __restrict__ eu_i, const float* __restrict__ ei_i,
    const float* __restrict__ eu_p, const float* __restrict__ ei_p,
    const int* __restrict__ map, const float* __restrict__ aggA, const float* __restrict__ aggB,
    float* __restrict__ dst) {
  int u = user[b], p = pos[b], n = neg[b];
  int su = map[u], sp = map[U_N + p], sn = map[U_N + n];
  float oui = eu_i[(size_t)u * D + lane] + aggA[(size_t)su * D + lane];
  float oup = eu_p[(size_t)u * D + lane] + aggB[(size_t)su * D + lane];
  float opi = ei_i[(size_t)p * D + lane] + aggA[(size_t)sp * D + lane];
  float opp = ei_p[(size_t)p * D + lane] + aggB[(size_t)sp * D + lane];
  float oni = ei_i[(size_t)n * D + lane] + aggA[(size_t)sn * D + lane];
  float onp = ei_p[(size_t)n * D + lane] + aggB[(size_t)sn * D + lane];
  float s0 = wave_sum(oui * opi);
  float s1 = wave_sum(oui * oni);
  float s2 = wave_sum(oup * opp);
  float s3 = wave_sum(oup * onp);
  if (lane == 0) {
    dst[b] = 0.25f * s0;
    dst[B + b] = 0.25f * s1;
    dst[2 * B + b] = 0.25f * s2;
    dst[3 * B + b] = 0.25f * s3;
  }
}

// Both graphs in one dispatch (big-ws path).
__global__ __launch_bounds__(256) void k_dots_pair(
    const int* __restrict__ user,
    const int* __restrict__ spos, const int* __restrict__ sneg,
    const int* __restrict__ tpos, const int* __restrict__ tneg,
    const float* __restrict__ su_i, const float* __restrict__ si_i,
    const float* __restrict__ su_p, const float* __restrict__ si_p,
    const float* __restrict__ tu_i, const float* __restrict__ ti_i,
    const float* __restrict__ tu_p, const float* __restrict__ ti_p,
    const int* __restrict__ map_s, const int* __restrict__ map_t,
    const float* __restrict__ aggSA, const float* __restrict__ aggSB,
    const float* __restrict__ aggTA, const float* __restrict__ aggTB,
    float* __restrict__ dots) {
  int lane = threadIdx.x & 63;
  int j = (blockIdx.x * blockDim.x + threadIdx.x) >> 6;
  if (j >= 2 * B) return;
  if (j < B) {
    dots_one(j, lane, user, spos, sneg, su_i, si_i, su_p, si_p, map_s, aggSA, aggSB, dots);
  } else {
    dots_one(j - B, lane, user, tpos, tneg, tu_i, ti_i, tu_p, ti_p, map_t, aggTA, aggTB,
             dots + 4 * B);
  }
}

// Single-graph variant (fallback path).
__global__ __launch_bounds__(256) void k_dots1(
    const int* __restrict__ user, const int* __restrict__ pos, const int* __restrict__ neg,
    const float* __restrict__ eu_i, const float* __restrict__ ei_i,
    const float* __restrict__ eu_p, const float* __restrict__ ei_p,
    const int* __restrict__ map, const float* __restrict__ aggA, const float* __restrict__ aggB,
    float* __restrict__ dst) {
  int lane = threadIdx.x & 63;
  int b = (blockIdx.x * blockDim.x + threadIdx.x) >> 6;
  if (b >= B) return;
  dots_one(b, lane, user, pos, neg, eu_i, ei_i, eu_p, ei_p, map, aggA, aggB, dst);
}

// ---------------------------------------------------------------------------
// Fused losses: blocks 0..31 do the BPR means; blocks 32.. do masked-L1.
__global__ __launch_bounds__(256) void k_loss(
    const unsigned char* __restrict__ ms8, const unsigned char* __restrict__ mt8,
    const float* __restrict__ dots, const int* __restrict__ det,
    const float* __restrict__ su_i, const float* __restrict__ su_p,
    const float* __restrict__ tu_i, const float* __restrict__ tu_p,
    const float* __restrict__ si_i, const float* __restrict__ si_p,
    const float* __restrict__ ti_i, const float* __restrict__ ti_p,
    const int* __restrict__ map_s, const int* __restrict__ map_t,
    float* __restrict__ acc) {
  if (blockIdx.x < 32) {
    int b = blockIdx.x * blockDim.x + threadIdx.x;  // < B exactly
    const float* spi = dots;
    const float* sni = dots + B;
    const float* spp = dots + 2 * B;
    const float* snp = dots + 3 * B;
    const float* tpi = dots + 4 * B;
    const float* tni = dots + 5 * B;
    const float* tpp = dots + 6 * B;
    const float* tnp = dots + 7 * B;
    int db = det[0], dc = det[1];
    float ms, mt;
    if (dc > 100) {
      ms = (((const float*)ms8)[b] != 0.f) ? 1.f : 0.f;
      mt = (((const float*)mt8)[b] != 0.f) ? 1.f : 0.f;
    } else if (db > 100) {
      ms = ms8[b] ? 1.f : 0.f;
      mt = mt8[b] ? 1.f : 0.f;
    } else {
      ms = ((const int*)ms8)[b] ? 1.f : 0.f;
      mt = ((const int*)mt8)[b] ? 1.f : 0.f;
    }
    float l_int_s = ms * softplus_f(sni[b] - spi[b]);
    float l_pop_s = ms * softplus_f(spp[b] - snp[b]) + (1.f - ms) * softplus_f(snp[b] - spp[b]);
    float l_tot_s = softplus_f((sni[b] + snp[b]) - (spi[b] + spp[b]));
    float l_int_t = mt * softplus_f(tni[b] - tpi[b]);
    float l_pop_t = mt * softplus_f(tpp[b] - tnp[b]) + (1.f - mt) * softplus_f(tnp[b] - tpp[b]);
    float l_tot_t = softplus_f((tni[b] + tnp[b]) - (tpi[b] + tpp[b]));
    float contrib = (l_tot_s + l_tot_t + 0.1f * (l_int_s + l_int_t) +
                     0.1f * (l_pop_s + l_pop_t)) * (1.f / (float)B);
#pragma unroll
    for (int off = 32; off; off >>= 1) contrib += __shfl_xor(contrib, off, 64);
    __shared__ float wsum_[4];
    if ((threadIdx.x & 63) == 0) wsum_[threadIdx.x >> 6] = contrib;
    __syncthreads();
    if (threadIdx.x == 0) atomicAdd(&acc[0], wsum_[0] + wsum_[1] + wsum_[2] + wsum_[3]);
    return;
  }
  // ---- masked-L1 over all three row segments ----
  int lane = threadIdx.x & 63;
  int wave = ((blockIdx.x - 32) * blockDim.x + threadIdx.x) >> 6;
  int nwaves = ((gridDim.x - 32) * blockDim.x) >> 6;
  float a1 = 0.f, a2 = 0.f, a3 = 0.f, a4 = 0.f;
  float c5 = 0.f, c6 = 0.f, c7 = 0.f;
  for (int r = wave; r < NROWS_ALL; r += nwaves) {
    if (r < U_N) {
      if (map_s[r] < 0) continue;
      size_t o = (size_t)r * D + lane;
      a1 += fabsf(su_i[o] - su_p[o]);
      a3 += fabsf(tu_i[o] - tu_p[o]);
      if (lane == 0) c5 += 1.f;
    } else if (r < U_N + SI_N) {
      int rr = r - U_N;
      if (map_s[U_N + rr] < 0) continue;
      size_t o = (size_t)rr * D + lane;
      a2 += fabsf(si_i[o] - si_p[o]);
      if (lane == 0) c6 += 1.f;
    } else {
      int rr = r - U_N - SI_N;
      if (map_t[U_N + rr] < 0) continue;
      size_t o = (size_t)rr * D + lane;
      a4 += fabsf(ti_i[o] - ti_p[o]);
      if (lane == 0) c7 += 1.f;
    }
  }
  a1 = wave_sum(a1);
  a2 = wave_sum(a2);
  a3 = wave_sum(a3);
  a4 = wave_sum(a4);
  __shared__ float sb[4][8];
  if (lane == 0) {
    int w = threadIdx.x >> 6;
    sb[w][0] = a1; sb[w][1] = a2; sb[w][2] = a3; sb[w][3] = a4;
    sb[w][4] = c5; sb[w][5] = c6; sb[w][6] = c7;
  }
  __syncthreads();
  int t = threadIdx.x;
  if (t < 7) {
    float v = sb[0][t] + sb[1][t] + sb[2][t] + sb[3][t];
    atomicAdd(&acc[1 + t], v);
  }
}

// ---------------------------------------------------------------------------
__global__ void k_final(const float* __restrict__ acc, float* __restrict__ out) {
  if (threadIdx.x == 0 && blockIdx.x == 0) {
    float cu = fmaxf(acc[5], 1.f);
    float cs = fmaxf(acc[6], 1.f);
    float ct = fmaxf(acc[7], 1.f);
    float dis = acc[1] / (cu * (float)D) + acc[2] / (cs * (float)D) +
                acc[3] / (cu * (float)D) + acc[4] / (ct * (float)D);
    out[0] = acc[0] - 0.01f * dis;
  }
}

// ---------------------------------------------------------------------------
extern "C" void kernel_launch(void* const* d_in, const int* in_sizes, int n_in,
                              void* d_out, int out_size, void* d_ws, size_t ws_size,
                              hipStream_t stream) {
  const int* user = (const int*)d_in[0];
  const int* spos = (const int*)d_in[1];
  const int* sneg = (const int*)d_in[2];
  const int* tpos = (const int*)d_in[3];
  const int* tneg = (const int*)d_in[4];
  const unsigned char* mask_s = (const unsigned char*)d_in[5];
  const unsigned char* mask_t = (const unsigned char*)d_in[6];
  const float* su_int = (const float*)d_in[7];
  const float* si_int = (const float*)d_in[8];
  const float* tu_int = (const float*)d_in[9];
  const float* ti_int = (const float*)d_in[10];
  const float* su_pop = (const float*)d_in[11];
  const float* si_pop = (const float*)d_in[12];
  const float* tu_pop = (const float*)d_in[13];
  const float* ti_pop = (const float*)d_in[14];
  const int* s_rows = (const int*)d_in[15];
  const int* s_cols = (const int*)d_in[16];
  const float* s_vals = (const float*)d_in[17];
  const int* t_rows = (const int*)d_in[18];
  const int* t_cols = (const int*)d_in[19];
  const float* t_vals = (const float*)d_in[20];
  const float* drop_s_int = (const float*)d_in[21];
  const float* drop_t_int = (const float*)d_in[22];
  const float* drop_s_pop = (const float*)d_in[23];
  const float* drop_t_pop = (const float*)d_in[24];
  const int nnz_s = in_sizes[15];
  const int nnz_t = in_sizes[18];

  // Workspace layout
  float* acc = (float*)d_ws;                        // 16 floats
  int* det = (int*)(acc + 16);                      // 2
  int* ovcnt_s = det + 2;                           // 1
  int* ovcnt_t = ovcnt_s + 1;                       // 1
  int* cnt_s = ovcnt_t + 1;                         // SLOTS
  int* cnt_t = cnt_s + SLOTS;                       // SLOTS
  int* map_s = cnt_t + SLOTS;                       // NS
  int* map_t = map_s + NS;                          // NT
  float* dots = (float*)(map_t + NT);               // 8*B
  int* ov_s = (int*)(dots + 8 * B);                 // 2*OVCAP
  int* ov_t = ov_s + 2 * OVCAP;                     // 2*OVCAP
  int* bucket_s = ov_t + 2 * OVCAP;                 // SLOTS*CAP
  int* bucket_t = bucket_s + SLOTS * CAP;           // SLOTS*CAP
  float* aggSA = (float*)(bucket_t + SLOTS * CAP);  // SLOTS*D
  float* aggSB = aggSA + (size_t)SLOTS * D;         // SLOTS*D
  float* aggTA = aggSB + (size_t)SLOTS * D;         // SLOTS*D (big-ws only)
  float* aggTB = aggTA + (size_t)SLOTS * D;         // SLOTS*D (big-ws only)
  size_t need_big = (size_t)((char*)(aggTB + (size_t)SLOTS * D) - (char*)d_ws);
  bool big = ws_size >= need_big;

  hipMemsetAsync(acc, 0, (size_t)(16 + 4 + 2 * SLOTS) * sizeof(int), stream);
  hipMemsetAsync(map_s, 0xFF, (size_t)(NS + NT) * sizeof(int), stream);

  k_init<<<97, 256, 0, stream>>>(user, spos, sneg, tpos, tneg, map_s, map_t, mask_s, det);

  k_compact2<<<(nnz_s + nnz_t + 255) / 256, 256, 0, stream>>>(
      s_rows, t_rows, map_s, map_t, cnt_s, cnt_t, bucket_s, bucket_t,
      ovcnt_s, ovcnt_t, ov_s, ov_t, nnz_s, nnz_t);

  if (big) {
    k_accum_pair<<<2 * SLOTS / 4, 256, 0, stream>>>(
        s_cols, s_vals, drop_s_int, drop_s_pop, t_cols, t_vals, drop_t_int, drop_t_pop,
        cnt_s, bucket_s, ovcnt_s, ov_s, cnt_t, bucket_t, ovcnt_t, ov_t,
        su_int, si_int, su_pop, si_pop, tu_int, ti_int, tu_pop, ti_pop,
        aggSA, aggSB, aggTA, aggTB);
    k_dots_pair<<<(2 * B * 64) / 256, 256, 0, stream>>>(
        user, spos, sneg, tpos, tneg, su_int, si_int, su_pop, si_pop,
        tu_int, ti_int, tu_pop, ti_pop, map_s, map_t,
        aggSA, aggSB, aggTA, aggTB, dots);
  } else {
    k_accum1<<<SLOTS / 4, 256, 0, stream>>>(s_cols, s_vals, drop_s_int, drop_s_pop,
                                            cnt_s, bucket_s, ovcnt_s, ov_s,
                                            su_int, si_int, su_pop, si_pop, aggSA, aggSB);
    k_dots1<<<(B * 64) / 256, 256, 0, stream>>>(user, spos, sneg, su_int, si_int, su_pop, si_pop,
                                                map_s, aggSA, aggSB, dots);
    k_accum1<<<SLOTS / 4, 256, 0, stream>>>(t_cols, t_vals, drop_t_int, drop_t_pop,
                                            cnt_t, bucket_t, ovcnt_t, ov_t,
                                            tu_int, ti_int, tu_pop, ti_pop, aggSA, aggSB);
    k_dots1<<<(B * 64) / 256, 256, 0, stream>>>(user, tpos, tneg, tu_int, ti_int, tu_pop, ti_pop,
                                                map_t, aggSA, aggSB, dots + 4 * B);
  }

  k_loss<<<32 + 256, 256, 0, stream>>>(mask_s, mask_t, dots, det,
                                       su_int, su_pop, tu_int, tu_pop,
                                       si_int, si_pop, ti_int, ti_pop,
                                       map_s, map_t, acc);
  k_final<<<1, 64, 0, stream>>>(acc, (float*)d_out);
}

// Round 6
// 484.860 us; speedup vs baseline: 4.1538x; 1.0127x over previous
//
#include <hip/hip_runtime.h>
#include <math.h>

// Problem constants (match reference file)
constexpr int U_N = 100000;
constexpr int SI_N = 50000;
constexpr int TI_N = 40000;
constexpr int D = 64;
constexpr int B = 8192;
constexpr int NS = U_N + SI_N;   // 150000 rows in source graph
constexpr int NT = U_N + TI_N;   // 140000 rows in target graph
constexpr int SLOTS = 3 * B;     // compact agg slots: users | pos items | neg items
constexpr int CAP = 64;          // bucket capacity per slot (Poisson lambda ~21)
constexpr int OVCAP = 4096;      // overflow list capacity (statistically never used)
constexpr int NROWS_ALL = U_N + SI_N + TI_N;  // fused dis-loss row space
constexpr int NCHUNK = (NROWS_ALL + 63) / 64; // 64-row chunks for L1 scan

__device__ __forceinline__ float wave_sum(float x) {
#pragma unroll
  for (int m = 32; m; m >>= 1) x += __shfl_xor(x, m, 64);
  return x;
}

__device__ __forceinline__ float softplus_f(float z) {
  return fmaxf(z, 0.f) + log1pf(expf(-fabsf(z)));
}

// ---------------------------------------------------------------------------
// Fused: blocks 0..95 build row->slot maps; block 96 classifies mask layout.
__global__ __launch_bounds__(256) void k_init(
    const int* __restrict__ user, const int* __restrict__ spos, const int* __restrict__ sneg,
    const int* __restrict__ tpos, const int* __restrict__ tneg,
    int* __restrict__ map_s, int* __restrict__ map_t,
    const unsigned char* __restrict__ m, int* __restrict__ det) {
  if (blockIdx.x < 96) {
    int t = blockIdx.x * blockDim.x + threadIdx.x;  // < 3*B exactly
    if (t < B) {
      int u = user[t];
      map_s[u] = t;
      map_t[u] = t;
    } else if (t < 2 * B) {
      int b = t - B;
      map_s[U_N + spos[b]] = t;
      map_t[U_N + tpos[b]] = t;
    } else {
      int b = t - 2 * B;
      map_s[U_N + sneg[b]] = t;
      map_t[U_N + tneg[b]] = t;
    }
    return;
  }
  int t = threadIdx.x;
  int cb = 0, cc = 0;
  for (int i = t; i < B; i += 256) {
    unsigned char v = m[i];
    if ((i & 3) && v) cb++;
    if (v > 1) cc++;
  }
#pragma unroll
  for (int off = 32; off; off >>= 1) {
    cb += __shfl_xor(cb, off, 64);
    cc += __shfl_xor(cc, off, 64);
  }
  __shared__ int sb[4], sc[4];
  if ((t & 63) == 0) { sb[t >> 6] = cb; sc[t >> 6] = cc; }
  __syncthreads();
  if (t == 0) {
    det[0] = sb[0] + sb[1] + sb[2] + sb[3];
    det[1] = sc[0] + sc[1] + sc[2] + sc[3];
  }
}

// ---------------------------------------------------------------------------
// Phase A (both graphs): one THREAD per edge; filter by map; bucket-append.
__global__ __launch_bounds__(256) void k_compact2(
    const int* __restrict__ s_rows, const int* __restrict__ t_rows,
    const int* __restrict__ map_s, const int* __restrict__ map_t,
    int* __restrict__ cnt_s, int* __restrict__ cnt_t,
    int* __restrict__ bucket_s, int* __restrict__ bucket_t,
    int* __restrict__ ovcnt_s, int* __restrict__ ovcnt_t,
    int* __restrict__ ov_s, int* __restrict__ ov_t, int nnz_s, int nnz_t) {
  int e = blockIdx.x * 256 + threadIdx.x;
  const int* rows;
  const int* map;
  int* cnt;
  int* bucket;
  int* ovcnt;
  int* ov;
  if (e < nnz_s) {
    rows = s_rows; map = map_s; cnt = cnt_s; bucket = bucket_s; ovcnt = ovcnt_s; ov = ov_s;
  } else {
    e -= nnz_s;
    if (e >= nnz_t) return;
    rows = t_rows; map = map_t; cnt = cnt_t; bucket = bucket_t; ovcnt = ovcnt_t; ov = ov_t;
  }
  int slot = map[rows[e]];
  if (slot < 0) return;
  int pos = atomicAdd(&cnt[slot], 1);
  if (pos < CAP) {
    bucket[slot * CAP + pos] = e;
  } else {
    int o = atomicAdd(ovcnt, 1);
    if (o < OVCAP) { ov[2 * o] = slot; ov[2 * o + 1] = e; }
  }
}

// ---------------------------------------------------------------------------
// Phase B helper: group g=lane>>4 handles edges k+g..k+12+g; sub=lane&15
// handles dims [4sub,4sub+4). 8 independent float4 loads in flight per iter.
__device__ __forceinline__ void accum_slot(
    int s, int lane,
    const int* __restrict__ cols, const float* __restrict__ vals,
    const float* __restrict__ di, const float* __restrict__ dp,
    const int* __restrict__ cnt, const int* __restrict__ bucket,
    const int* __restrict__ ovcnt, const int* __restrict__ ov,
    const float* __restrict__ eu_i, const float* __restrict__ ei_i,
    const float* __restrict__ eu_p, const float* __restrict__ ei_p,
    float* __restrict__ aggA, float* __restrict__ aggB) {
  int m = min(cnt[s], CAP);
  int g = lane >> 4, sub = lane & 15;
  int c = 0;
  float wi = 0.f, wp = 0.f;
  if (lane < m) {
    int e = bucket[s * CAP + lane];
    c = cols[e];
    float v = vals[e];
    wi = v * di[e];
    wp = v * dp[e];
  }
  float aIx = 0, aIy = 0, aIz = 0, aIw = 0;
  float aPx = 0, aPy = 0, aPz = 0, aPw = 0;
  for (int k = 0; k < m; k += 16) {
    int i0 = k + g, i1 = k + 4 + g, i2 = k + 8 + g, i3 = k + 12 + g;  // <= 63
    int c0 = __shfl(c, i0, 64), c1 = __shfl(c, i1, 64);
    int c2 = __shfl(c, i2, 64), c3 = __shfl(c, i3, 64);
    float wi0 = __shfl(wi, i0, 64), wi1 = __shfl(wi, i1, 64);
    float wi2 = __shfl(wi, i2, 64), wi3 = __shfl(wi, i3, 64);
    float wp0 = __shfl(wp, i0, 64), wp1 = __shfl(wp, i1, 64);
    float wp2 = __shfl(wp, i2, 64), wp3 = __shfl(wp, i3, 64);
    const float* bi0 = (c0 < U_N) ? (eu_i + (size_t)c0 * D) : (ei_i + (size_t)(c0 - U_N) * D);
    const float* bi1 = (c1 < U_N) ? (eu_i + (size_t)c1 * D) : (ei_i + (size_t)(c1 - U_N) * D);
    const float* bi2 = (c2 < U_N) ? (eu_i + (size_t)c2 * D) : (ei_i + (size_t)(c2 - U_N) * D);
    const float* bi3 = (c3 < U_N) ? (eu_i + (size_t)c3 * D) : (ei_i + (size_t)(c3 - U_N) * D);
    const float* bp0 = (c0 < U_N) ? (eu_p + (size_t)c0 * D) : (ei_p + (size_t)(c0 - U_N) * D);
    const float* bp1 = (c1 < U_N) ? (eu_p + (size_t)c1 * D) : (ei_p + (size_t)(c1 - U_N) * D);
    const float* bp2 = (c2 < U_N) ? (eu_p + (size_t)c2 * D) : (ei_p + (size_t)(c2 - U_N) * D);
    const float* bp3 = (c3 < U_N) ? (eu_p + (size_t)c3 * D) : (ei_p + (size_t)(c3 - U_N) * D);
    float4 vI0 = *(const float4*)(bi0 + 4 * sub);
    float4 vI1 = *(const float4*)(bi1 + 4 * sub);
    float4 vI2 = *(const float4*)(bi2 + 4 * sub);
    float4 vI3 = *(const float4*)(bi3 + 4 * sub);
    float4 vP0 = *(const float4*)(bp0 + 4 * sub);
    float4 vP1 = *(const float4*)(bp1 + 4 * sub);
    float4 vP2 = *(const float4*)(bp2 + 4 * sub);
    float4 vP3 = *(const float4*)(bp3 + 4 * sub);
    aIx = fmaf(wi0, vI0.x, aIx); aIy = fmaf(wi0, vI0.y, aIy);
    aIz = fmaf(wi0, vI0.z, aIz); aIw = fmaf(wi0, vI0.w, aIw);
    aIx = fmaf(wi1, vI1.x, aIx); aIy = fmaf(wi1, vI1.y, aIy);
    aIz = fmaf(wi1, vI1.z, aIz); aIw = fmaf(wi1, vI1.w, aIw);
    aIx = fmaf(wi2, vI2.x, aIx); aIy = fmaf(wi2, vI2.y, aIy);
    aIz = fmaf(wi2, vI2.z, aIz); aIw = fmaf(wi2, vI2.w, aIw);
    aIx = fmaf(wi3, vI3.x, aIx); aIy = fmaf(wi3, vI3.y, aIy);
    aIz = fmaf(wi3, vI3.z, aIz); aIw = fmaf(wi3, vI3.w, aIw);
    aPx = fmaf(wp0, vP0.x, aPx); aPy = fmaf(wp0, vP0.y, aPy);
    aPz = fmaf(wp0, vP0.z, aPz); aPw = fmaf(wp0, vP0.w, aPw);
    aPx = fmaf(wp1, vP1.x, aPx); aPy = fmaf(wp1, vP1.y, aPy);
    aPz = fmaf(wp1, vP1.z, aPz); aPw = fmaf(wp1, vP1.w, aPw);
    aPx = fmaf(wp2, vP2.x, aPx); aPy = fmaf(wp2, vP2.y, aPy);
    aPz = fmaf(wp2, vP2.z, aPz); aPw = fmaf(wp2, vP2.w, aPw);
    aPx = fmaf(wp3, vP3.x, aPx); aPy = fmaf(wp3, vP3.y, aPy);
    aPz = fmaf(wp3, vP3.z, aPz); aPw = fmaf(wp3, vP3.w, aPw);
  }
#define XRED(x) x += __shfl_xor(x, 16, 64); x += __shfl_xor(x, 32, 64);
  XRED(aIx) XRED(aIy) XRED(aIz) XRED(aIw)
  XRED(aPx) XRED(aPy) XRED(aPz) XRED(aPw)
#undef XRED
  // overflow fixup by owner wave (normally nov==0)
  int nov = min(*ovcnt, OVCAP);
  for (int i = 0; i < nov; ++i) {
    if (ov[2 * i] == s) {
      int e = ov[2 * i + 1];
      int cc = cols[e];
      float v = vals[e];
      float wwi = v * di[e], wwp = v * dp[e];
      const float* bi = (cc < U_N) ? (eu_i + (size_t)cc * D) : (ei_i + (size_t)(cc - U_N) * D);
      const float* bp = (cc < U_N) ? (eu_p + (size_t)cc * D) : (ei_p + (size_t)(cc - U_N) * D);
      if (lane < 16) {
        float4 vI = *(const float4*)(bi + 4 * sub);
        float4 vP = *(const float4*)(bp + 4 * sub);
        aIx = fmaf(wwi, vI.x, aIx); aIy = fmaf(wwi, vI.y, aIy);
        aIz = fmaf(wwi, vI.z, aIz); aIw = fmaf(wwi, vI.w, aIw);
        aPx = fmaf(wwp, vP.x, aPx); aPy = fmaf(wwp, vP.y, aPy);
        aPz = fmaf(wwp, vP.z, aPz); aPw = fmaf(wwp, vP.w, aPw);
      }
    }
  }
  if (lane < 16) {
    *(float4*)(aggA + (size_t)s * D + 4 * sub) = make_float4(aIx, aIy, aIz, aIw);
    *(float4*)(aggB + (size_t)s * D + 4 * sub) = make_float4(aPx, aPy, aPz, aPw);
  }
}

// Both graphs in one dispatch: sg<SLOTS source, else target.
__global__ __launch_bounds__(256) void k_accum_pair(
    const int* __restrict__ s_cols, const float* __restrict__ s_vals,
    const float* __restrict__ dsi, const float* __restrict__ dsp,
    const int* __restrict__ t_cols, const float* __restrict__ t_vals,
    const float* __restrict__ dti, const float* __restrict__ dtp,
    const int* __restrict__ cnt_s, const int* __restrict__ bucket_s,
    const int* __restrict__ ovcnt_s, const int* __restrict__ ov_s,
    const int* __restrict__ cnt_t, const int* __restrict__ bucket_t,
    const int* __restrict__ ovcnt_t, const int* __restrict__ ov_t,
    const float* __restrict__ su_i, const float* __restrict__ si_i,
    const float* __restrict__ su_p, const float* __restrict__ si_p,
    const float* __restrict__ tu_i, const float* __restrict__ ti_i,
    const float* __restrict__ tu_p, const float* __restrict__ ti_p,
    float* __restrict__ aggSA, float* __restrict__ aggSB,
    float* __restrict__ aggTA, float* __restrict__ aggTB) {
  int lane = threadIdx.x & 63;
  int sg = (blockIdx.x * 256 + threadIdx.x) >> 6;
  if (sg >= 2 * SLOTS) return;
  if (sg < SLOTS) {
    accum_slot(sg, lane, s_cols, s_vals, dsi, dsp, cnt_s, bucket_s, ovcnt_s, ov_s,
               su_i, si_i, su_p, si_p, aggSA, aggSB);
  } else {
    accum_slot(sg - SLOTS, lane, t_cols, t_vals, dti, dtp, cnt_t, bucket_t, ovcnt_t, ov_t,
               tu_i, ti_i, tu_p, ti_p, aggTA, aggTB);
  }
}

// ---------------------------------------------------------------------------
// One wave per sample: compute all 8 dots (both graphs) AND the per-sample BPR
// losses directly; block-reduce; one atomic per block into acc[0].
__global__ __launch_bounds__(256) void k_dots_loss(
    const int* __restrict__ user,
    const int* __restrict__ spos, const int* __restrict__ sneg,
    const int* __restrict__ tpos, const int* __restrict__ tneg,
    const unsigned char* __restrict__ ms8, const unsigned char* __restrict__ mt8,
    const int* __restrict__ det,
    const float* __restrict__ su_i, const float* __restrict__ si_i,
    const float* __restrict__ su_p, const float* __restrict__ si_p,
    const float* __restrict__ tu_i, const float* __restrict__ ti_i,
    const float* __restrict__ tu_p, const float* __restrict__ ti_p,
    const int* __restrict__ map_s, const int* __restrict__ map_t,
    const float* __restrict__ aggSA, const float* __restrict__ aggSB,
    const float* __restrict__ aggTA, const float* __restrict__ aggTB,
    float* __restrict__ acc) {
  int lane = threadIdx.x & 63;
  int b = (blockIdx.x * blockDim.x + threadIdx.x) >> 6;
  float contrib = 0.f;
  if (b < B) {
    int u = user[b];
    int ps = spos[b], ns = sneg[b], pt = tpos[b], nt = tneg[b];
    int sus = map_s[u], sps = map_s[U_N + ps], sns = map_s[U_N + ns];
    int sut = map_t[u], spt = map_t[U_N + pt], snt = map_t[U_N + nt];
    // source graph
    float oui = su_i[(size_t)u * D + lane] + aggSA[(size_t)sus * D + lane];
    float oup = su_p[(size_t)u * D + lane] + aggSB[(size_t)sus * D + lane];
    float opi = si_i[(size_t)ps * D + lane] + aggSA[(size_t)sps * D + lane];
    float opp = si_p[(size_t)ps * D + lane] + aggSB[(size_t)sps * D + lane];
    float oni = si_i[(size_t)ns * D + lane] + aggSA[(size_t)sns * D + lane];
    float onp = si_p[(size_t)ns * D + lane] + aggSB[(size_t)sns * D + lane];
    float spi = 0.25f * wave_sum(oui * opi);
    float sni = 0.25f * wave_sum(oui * oni);
    float spp = 0.25f * wave_sum(oup * opp);
    float snp = 0.25f * wave_sum(oup * onp);
    // target graph
    float tui = tu_i[(size_t)u * D + lane] + aggTA[(size_t)sut * D + lane];
    float tup = tu_p[(size_t)u * D + lane] + aggTB[(size_t)sut * D + lane];
    float tpi_ = ti_i[(size_t)pt * D + lane] + aggTA[(size_t)spt * D + lane];
    float tpp_ = ti_p[(size_t)pt * D + lane] + aggTB[(size_t)spt * D + lane];
    float tni_ = ti_i[(size_t)nt * D + lane] + aggTA[(size_t)snt * D + lane];
    float tnp_ = ti_p[(size_t)nt * D + lane] + aggTB[(size_t)snt * D + lane];
    float tpi = 0.25f * wave_sum(tui * tpi_);
    float tni = 0.25f * wave_sum(tui * tni_);
    float tpp = 0.25f * wave_sum(tup * tpp_);
    float tnp = 0.25f * wave_sum(tup * tnp_);
    // masks
    int db = det[0], dc = det[1];
    float ms, mt;
    if (dc > 100) {
      ms = (((const float*)ms8)[b] != 0.f) ? 1.f : 0.f;
      mt = (((const float*)mt8)[b] != 0.f) ? 1.f : 0.f;
    } else if (db > 100) {
      ms = ms8[b] ? 1.f : 0.f;
      mt = mt8[b] ? 1.f : 0.f;
    } else {
      ms = ((const int*)ms8)[b] ? 1.f : 0.f;
      mt = ((const int*)mt8)[b] ? 1.f : 0.f;
    }
    float l_int_s = ms * softplus_f(sni - spi);
    float l_pop_s = ms * softplus_f(spp - snp) + (1.f - ms) * softplus_f(snp - spp);
    float l_tot_s = softplus_f((sni + snp) - (spi + spp));
    float l_int_t = mt * softplus_f(tni - tpi);
    float l_pop_t = mt * softplus_f(tpp - tnp) + (1.f - mt) * softplus_f(tnp - tpp);
    float l_tot_t = softplus_f((tni + tnp) - (tpi + tpp));
    contrib = (l_tot_s + l_tot_t + 0.1f * (l_int_s + l_int_t) +
               0.1f * (l_pop_s + l_pop_t)) * (1.f / (float)B);
  }
  __shared__ float wsum_[4];
  if (lane == 0) wsum_[threadIdx.x >> 6] = contrib;  // contrib is wave-uniform
  __syncthreads();
  if (threadIdx.x == 0) atomicAdd(&acc[0], wsum_[0] + wsum_[1] + wsum_[2] + wsum_[3]);
}

// ---------------------------------------------------------------------------
// Masked-L1 over all row segments via COALESCED 64-row chunk flag scans.
// Each wave: one coalesced map load covers 64 rows; survivors via ballot.
// acc[1..4]=L1 numerators, acc[5..7]=distinct counts. Last block computes out.
__global__ __launch_bounds__(256) void k_l1_final(
    const float* __restrict__ su_i, const float* __restrict__ su_p,
    const float* __restrict__ tu_i, const float* __restrict__ tu_p,
    const float* __restrict__ si_i, const float* __restrict__ si_p,
    const float* __restrict__ ti_i, const float* __restrict__ ti_p,
    const int* __restrict__ map_s, const int* __restrict__ map_t,
    float* __restrict__ acc, int* __restrict__ done_ctr,
    float* __restrict__ out) {
  int lane = threadIdx.x & 63;
  int wave = (blockIdx.x * blockDim.x + threadIdx.x) >> 6;
  int nwaves = (gridDim.x * blockDim.x) >> 6;
  float a1 = 0.f, a2 = 0.f, a3 = 0.f, a4 = 0.f;
  float c5 = 0.f, c6 = 0.f, c7 = 0.f;
  for (int ch = wave; ch < NCHUNK; ch += nwaves) {
    int r0 = ch * 64;
    int r = r0 + lane;
    int flag = -1;
    if (r < NROWS_ALL) flag = (r < NS) ? map_s[r] : map_t[r - SI_N];
    bool valid = flag >= 0;
    unsigned long long m0 = __ballot(valid && r < U_N);
    unsigned long long m1 = __ballot(valid && r >= U_N && r < NS);
    unsigned long long m2 = __ballot(valid && r >= NS);
    if (lane == 0) {
      c5 += (float)__popcll(m0);
      c6 += (float)__popcll(m1);
      c7 += (float)__popcll(m2);
    }
    unsigned long long mm = m0 | m1 | m2;
    while (mm) {
      int bit = __ffsll((unsigned long long)mm) - 1;
      mm &= mm - 1;
      int rr = r0 + bit;
      if (rr < U_N) {
        size_t o = (size_t)rr * D + lane;
        a1 += fabsf(su_i[o] - su_p[o]);
        a3 += fabsf(tu_i[o] - tu_p[o]);
      } else if (rr < NS) {
        size_t o = (size_t)(rr - U_N) * D + lane;
        a2 += fabsf(si_i[o] - si_p[o]);
      } else {
        size_t o = (size_t)(rr - NS) * D + lane;
        a4 += fabsf(ti_i[o] - ti_p[o]);
      }
    }
  }
  a1 = wave_sum(a1);
  a2 = wave_sum(a2);
  a3 = wave_sum(a3);
  a4 = wave_sum(a4);
  __shared__ float sb[4][8];
  if (lane == 0) {
    int w = threadIdx.x >> 6;
    sb[w][0] = a1; sb[w][1] = a2; sb[w][2] = a3; sb[w][3] = a4;
    sb[w][4] = c5; sb[w][5] = c6; sb[w][6] = c7;
  }
  __syncthreads();
  int t = threadIdx.x;
  if (t < 7) {
    float v = sb[0][t] + sb[1][t] + sb[2][t] + sb[3][t];
    atomicAdd(&acc[1 + t], v);
  }
  __syncthreads();
  if (t == 0) {
    __threadfence();
    int old = atomicAdd(done_ctr, 1);
    if (old == (int)gridDim.x - 1) {
      // all blocks' acc atomics are visible (fence before each increment)
      float a0 = atomicAdd(&acc[0], 0.f);
      float n1 = atomicAdd(&acc[1], 0.f);
      float n2 = atomicAdd(&acc[2], 0.f);
      float n3 = atomicAdd(&acc[3], 0.f);
      float n4 = atomicAdd(&acc[4], 0.f);
      float cu = fmaxf(atomicAdd(&acc[5], 0.f), 1.f);
      float cs = fmaxf(atomicAdd(&acc[6], 0.f), 1.f);
      float ct = fmaxf(atomicAdd(&acc[7], 0.f), 1.f);
      float dis = n1 / (cu * (float)D) + n2 / (cs * (float)D) +
                  n3 / (cu * (float)D) + n4 / (ct * (float)D);
      out[0] = a0 - 0.01f * dis;
    }
  }
}

// ---------------------------------------------------------------------------
extern "C" void kernel_launch(void* const* d_in, const int* in_sizes, int n_in,
                              void* d_out, int out_size, void* d_ws, size_t ws_size,
                              hipStream_t stream) {
  const int* user = (const int*)d_in[0];
  const int* spos = (const int*)d_in[1];
  const int* sneg = (const int*)d_in[2];
  const int* tpos = (const int*)d_in[3];
  const int* tneg = (const int*)d_in[4];
  const unsigned char* mask_s = (const unsigned char*)d_in[5];
  const unsigned char* mask_t = (const unsigned char*)d_in[6];
  const float* su_int = (const float*)d_in[7];
  const float* si_int = (const float*)d_in[8];
  const float* tu_int = (const float*)d_in[9];
  const float* ti_int = (const float*)d_in[10];
  const float* su_pop = (const float*)d_in[11];
  const float* si_pop = (const float*)d_in[12];
  const float* tu_pop = (const float*)d_in[13];
  const float* ti_pop = (const float*)d_in[14];
  const int* s_rows = (const int*)d_in[15];
  const int* s_cols = (const int*)d_in[16];
  const float* s_vals = (const float*)d_in[17];
  const int* t_rows = (const int*)d_in[18];
  const int* t_cols = (const int*)d_in[19];
  const float* t_vals = (const float*)d_in[20];
  const float* drop_s_int = (const float*)d_in[21];
  const float* drop_t_int = (const float*)d_in[22];
  const float* drop_s_pop = (const float*)d_in[23];
  const float* drop_t_pop = (const float*)d_in[24];
  const int nnz_s = in_sizes[15];
  const int nnz_t = in_sizes[18];

  // Workspace layout (~46 MB)
  float* acc = (float*)d_ws;                        // 16 floats
  int* done_ctr = (int*)(acc + 16);                 // 1
  int* det = done_ctr + 1;                          // 2
  int* ovcnt_s = det + 2;                           // 1
  int* ovcnt_t = ovcnt_s + 1;                       // 1
  int* cnt_s = ovcnt_t + 1;                         // SLOTS
  int* cnt_t = cnt_s + SLOTS;                       // SLOTS
  int* map_s = cnt_t + SLOTS;                       // NS
  int* map_t = map_s + NS;                          // NT
  int* ov_s = map_t + NT;                           // 2*OVCAP
  int* ov_t = ov_s + 2 * OVCAP;                     // 2*OVCAP
  int* bucket_s = ov_t + 2 * OVCAP;                 // SLOTS*CAP
  int* bucket_t = bucket_s + SLOTS * CAP;           // SLOTS*CAP
  float* aggSA = (float*)(bucket_t + SLOTS * CAP);  // SLOTS*D
  float* aggSB = aggSA + (size_t)SLOTS * D;         // SLOTS*D
  float* aggTA = aggSB + (size_t)SLOTS * D;         // SLOTS*D
  float* aggTB = aggTA + (size_t)SLOTS * D;         // SLOTS*D

  // zero acc..cnt_t (contiguous); maps to -1
  hipMemsetAsync(acc, 0, (size_t)(16 + 1 + 2 + 2 + 2 * SLOTS) * sizeof(int), stream);
  hipMemsetAsync(map_s, 0xFF, (size_t)(NS + NT) * sizeof(int), stream);

  k_init<<<97, 256, 0, stream>>>(user, spos, sneg, tpos, tneg, map_s, map_t, mask_s, det);

  k_compact2<<<(nnz_s + nnz_t + 255) / 256, 256, 0, stream>>>(
      s_rows, t_rows, map_s, map_t, cnt_s, cnt_t, bucket_s, bucket_t,
      ovcnt_s, ovcnt_t, ov_s, ov_t, nnz_s, nnz_t);

  k_accum_pair<<<2 * SLOTS / 4, 256, 0, stream>>>(
      s_cols, s_vals, drop_s_int, drop_s_pop, t_cols, t_vals, drop_t_int, drop_t_pop,
      cnt_s, bucket_s, ovcnt_s, ov_s, cnt_t, bucket_t, ovcnt_t, ov_t,
      su_int, si_int, su_pop, si_pop, tu_int, ti_int, tu_pop, ti_pop,
      aggSA, aggSB, aggTA, aggTB);

  k_dots_loss<<<(B + 3) / 4, 256, 0, stream>>>(
      user, spos, sneg, tpos, tneg, mask_s, mask_t, det,
      su_int, si_int, su_pop, si_pop, tu_int, ti_int, tu_pop, ti_pop,
      map_s, map_t, aggSA, aggSB, aggTA, aggTB, acc);

  k_l1_final<<<768, 256, 0, stream>>>(su_int, su_pop, tu_int, tu_pop,
                                      si_int, si_pop, ti_int, ti_pop,
                                      map_s, map_t, acc, done_ctr, (float*)d_out);
}